// Round 4
// baseline (3519.490 us; speedup 1.0000x reference)
//
#include <hip/hip_runtime.h>
#include <hip/hip_bf16.h>

#define B_ 16
#define N_ 358
#define P_ 72
#define D_ 96
#define ND_ 64
#define H_ 4
#define NH_ 4
#define HD_ 24
#define K_ 10
#define BN_ (B_*N_)     /* 5728 */
#define NN_ (N_*N_)     /* 128164 */
#define RPW_ 6          /* ceil(358/64) elements per lane in wave-per-row kernels */
#define NR5 5           /* rows per 32-lane group in attn (16 groups x 5 = 80 padded rows) */

__device__ __forceinline__ float gelu_f(float x){ return 0.5f*x*(1.0f+erff(x*0.7071067811865476f)); }
__device__ __forceinline__ float sigm_f(float x){ return 1.0f/(1.0f+expf(-x)); }

// ---------------------------------------------------------------------------
// Kernel 0: transpose the 96x96 weight matrices (wq,wk,wv,wo) into workspace
// so attn's weight loads become b128 along k. Runs once, ~147KB, trivial cost.
// ---------------------------------------------------------------------------
__global__ __launch_bounds__(256) void transw_kernel(
    const float* __restrict__ wq, const float* __restrict__ wk,
    const float* __restrict__ wv, const float* __restrict__ wo,
    float* __restrict__ wqT, float* __restrict__ wkT,
    float* __restrict__ wvT, float* __restrict__ woT)
{
    const int gid = blockIdx.x*256 + threadIdx.x;
    if (gid >= 4*D_*D_) return;
    const int mat = gid / (D_*D_);
    const int idx = gid - mat*(D_*D_);
    const int c = idx / D_, k = idx - c*D_;      // dst[c][k] = src[k][c]
    const float* src = (mat==0)?wq:(mat==1)?wk:(mat==2)?wv:wo;
    float* dst = (mat==0)?wqT:(mat==1)?wkT:(mat==2)?wvT:woT;
    dst[idx] = src[k*D_ + c];
}

// ---------------------------------------------------------------------------
// Kernel 1: temporal attention + node embedding (one block per (b,n) sequence)
//
// LAUNCH-BOUNDS SCAR (R1, measured): 2nd __launch_bounds__ arg acts like CUDA
// minBlocksPerMultiprocessor here: (512,4) -> VGPR cap 64 -> 33 GB spill.
// (512,2) -> 16 waves/CU, cap 128 (VGPR=128 confirmed R2; 80 in R3).
//
// SPILL SCAR (R2, measured): chunk-4 temps WITHOUT "#pragma unroll 1"
// overflowed the 128 cap (6.9 GB scratch). R3 proved unroll-1 + chunk-2 = 80
// regs. R4 restores chunk-4 WITH unroll-1 (temps ~47, peak ~105) — margin OK.
//
// INSTRUCTION-COUNT SCAR (R3, measured): occupancy 2x (37->52 VALUBusy) gave
// ~0 speedup because per-FMA VALU overhead rose ~4x (pad rows, chunk-2,
// address recompute). R4 cuts instructions: transposed-weight b128 loads
// (1 load + 1 addr per 4 weights), b128 K-fragments via kh[96][28],
// chunk-4 loops, __expf.
//
// LDS pool (floats): qh[80][28]=2240 @0 | kh[96][28]=2688 @2240 |
//  vhT[24][84]=2016 @4928 | att[80][76]=6080 @6944 | obuf[80][28]=2240 @13024
//  xs/ats [80][100]=8000 @0 (phase-1/epilogue, overlap is phase-ordered).
//  Total 15264 floats = 61.1KB -> 2 blocks/CU. kh rows 80..95 are never
//  written (garbage); they only feed the masked j=2 slot (lanes tc>=8 never
//  consume sc[2]) — safe.
// ---------------------------------------------------------------------------
__global__ __launch_bounds__(512, 2) void attn_kernel(
    const float* __restrict__ patch, const float* __restrict__ pos,
    const float* __restrict__ wqT, const float* __restrict__ bq,
    const float* __restrict__ wkT, const float* __restrict__ bk,
    const float* __restrict__ wvT, const float* __restrict__ bv,
    const float* __restrict__ woT, const float* __restrict__ bo,
    const float* __restrict__ tng, const float* __restrict__ tnb,
    float* __restrict__ node_out, float* __restrict__ meanpr_out)
{
    __shared__ __align__(16) float pool[15264];
    __shared__ float rr[80];
    __shared__ float nb[D_];
    __shared__ float st2[2];

    float* const xs   = pool;           // [80][100] phase 1
    float* const qh   = pool;           // [80][28]
    float* const kh   = pool + 2240;    // [96][28]
    float* const vhT  = pool + 4928;    // [24][84]
    float* const att  = pool + 6944;    // [80][76]
    float* const obuf = pool + 13024;   // [80][28]
    float* const ats  = pool;           // [80][100] epilogue

    const int tid = threadIdx.x;
    const int tc  = tid & 31;
    const int tr  = tid >> 5;           // 0..15
    const int rbase = tr * NR5;         // 0,5,...,75
    const int bn  = blockIdx.x;
    const float* pr = patch + (size_t)bn * (P_*D_);

    // mean over P of pr (node_f) -- kept in a register by threads tid<96
    float mpr = 0.f;
    if (tid < D_) {
        #pragma unroll 1
        for (int p = 0; p < P_; ++p) mpr += pr[p*D_+tid];
        mpr *= (1.0f/P_);
        meanpr_out[(size_t)bn*D_ + tid] = mpr;
    }

    // load X = pr + pos into LDS [80][100]; rows 72..79 and cols 96..99 zero
    #pragma unroll 1
    for (int e = tid; e < 80*100; e += 512) {
        const int row = e / 100, col = e - row*100;
        xs[e] = (row < P_ && col < D_) ? (pr[row*D_+col] + pos[row*D_+col]) : 0.f;
    }
    __syncthreads();

    // ---- phase 1: Q,K,V = X @ W + b; transposed weights -> b128 loads ----
    float aq[3][NR5], ak[3][NR5], av[3][NR5];

#define P1_LOOP(WTP, BP, ACC)                                                \
    {                                                                        \
        _Pragma("unroll")                                                    \
        for (int j = 0; j < 3; ++j) {                                        \
            const float vb = BP[tc + 32*j];                                  \
            _Pragma("unroll")                                                \
            for (int i = 0; i < NR5; ++i) ACC[j][i] = vb;                    \
        }                                                                    \
        _Pragma("unroll 1")                                                  \
        for (int k0 = 0; k0 < D_; k0 += 4) {                                 \
            float4 xv[NR5];                                                  \
            _Pragma("unroll")                                                \
            for (int i = 0; i < NR5; ++i)                                    \
                xv[i] = *reinterpret_cast<const float4*>(&xs[(rbase+i)*100 + k0]); \
            float4 w4[3];                                                    \
            _Pragma("unroll")                                                \
            for (int j = 0; j < 3; ++j)                                      \
                w4[j] = *reinterpret_cast<const float4*>(&WTP[(tc+32*j)*D_ + k0]); \
            _Pragma("unroll")                                                \
            for (int j = 0; j < 3; ++j)                                      \
                _Pragma("unroll")                                            \
                for (int i = 0; i < NR5; ++i)                                \
                    ACC[j][i] += xv[i].x*w4[j].x + xv[i].y*w4[j].y           \
                               + xv[i].z*w4[j].z + xv[i].w*w4[j].w;          \
        }                                                                    \
    }

    P1_LOOP(wqT, bq, aq)
    P1_LOOP(wkT, bk, ak)
    P1_LOOP(wvT, bv, av)
#undef P1_LOOP

    __syncthreads();        // all xs reads done; pool free for head buffers

    const float rs = 0.20412414523193154f;      // 1/sqrt(24)

    // attended accumulators (output of o @ wo + bo), live across heads
    float ao[3][NR5];
    #pragma unroll
    for (int j = 0; j < 3; ++j) {
        const float vbo = bo[tc + 32*j];
        #pragma unroll
        for (int i = 0; i < NR5; ++i) ao[j][i] = vbo;
    }

    // stage head hh's Q (pre-scaled by rs), K, V^T slices from registers
    auto stage = [&](int hh) {
        #pragma unroll
        for (int j = 0; j < 3; ++j) {
            const int c = tc + 32*j;
            const int dl = c - HD_*hh;
            if ((unsigned)dl < (unsigned)HD_) {
                #pragma unroll
                for (int i = 0; i < NR5; ++i) {
                    const int row = rbase + i;
                    qh [row*28 + dl] = aq[j][i] * rs;
                    kh [row*28 + dl] = ak[j][i];
                    vhT[dl*84 + row] = av[j][i];
                }
            }
        }
    };

    stage(0);
    __syncthreads();    // A0: head-0 qh/kh/vhT visible

    #pragma unroll 1
    for (int h = 0; h < NH_; ++h) {
        // ---- scores S = (Q*rs) K^T, rows rbase..+4, cols jn = tc+32*j ----
        // chunk 4, b128 both sides (kh rows >=80 are masked garbage)
        float sc[3][NR5];
        #pragma unroll
        for (int j = 0; j < 3; ++j)
            #pragma unroll
            for (int i = 0; i < NR5; ++i) sc[j][i] = 0.f;
        #pragma unroll 1
        for (int d0 = 0; d0 < HD_; d0 += 4) {
            float4 qv[NR5];
            #pragma unroll
            for (int i = 0; i < NR5; ++i)
                qv[i] = *reinterpret_cast<const float4*>(&qh[(rbase+i)*28 + d0]);
            float4 kv[3];
            #pragma unroll
            for (int j = 0; j < 3; ++j) {
                const int jn = tc + 32*j;       // <=95 < 96 rows of kh
                kv[j] = *reinterpret_cast<const float4*>(&kh[jn*28 + d0]);
            }
            #pragma unroll
            for (int j = 0; j < 3; ++j)
                #pragma unroll
                for (int i = 0; i < NR5; ++i)
                    sc[j][i] += qv[i].x*kv[j].x + qv[i].y*kv[j].y
                              + qv[i].z*kv[j].z + qv[i].w*kv[j].w;
        }

        // ---- in-register row softmax (row owned by one 32-lane group) ----
        #pragma unroll
        for (int i = 0; i < NR5; ++i) {
            float m = fmaxf(sc[0][i], sc[1][i]);
            if (tc < 8) m = fmaxf(m, sc[2][i]);         // jn=64+tc valid iff tc<8
            #pragma unroll
            for (int s = 1; s < 32; s <<= 1) m = fmaxf(m, __shfl_xor(m, s, 32));
            const float e0 = __expf(sc[0][i]-m);
            const float e1 = __expf(sc[1][i]-m);
            const float e2 = (tc < 8) ? __expf(sc[2][i]-m) : 0.f;
            float sm = e0 + e1 + e2;
            #pragma unroll
            for (int s = 1; s < 32; s <<= 1) sm += __shfl_xor(sm, s, 32);
            const float inv = 1.0f/sm;
            const int row = rbase + i;
            att[row*76 + tc]      = e0*inv;
            att[row*76 + tc + 32] = e1*inv;
            if (tc < 8) att[row*76 + tc + 64] = e2*inv;
        }
        __syncthreads();    // B: P visible; qh/kh reads done

        // ---- PV: O[row][tc] = sum_j P[row][j] V[j][tc]  (tc < 24) ----
        if (tc < HD_) {
            float ov[NR5];
            #pragma unroll
            for (int i = 0; i < NR5; ++i) ov[i] = 0.f;
            #pragma unroll 1
            for (int j0 = 0; j0 < P_; j0 += 4) {
                const float4 vv = *reinterpret_cast<const float4*>(&vhT[tc*84 + j0]);
                #pragma unroll
                for (int i = 0; i < NR5; ++i) {
                    const float4 pa = *reinterpret_cast<const float4*>(&att[(rbase+i)*76 + j0]);
                    ov[i] += pa.x*vv.x + pa.y*vv.y + pa.z*vv.z + pa.w*vv.w;
                }
            }
            #pragma unroll
            for (int i = 0; i < NR5; ++i) obuf[(rbase+i)*28 + tc] = ov[i];
        }
        __syncthreads();    // C: O visible; att/vhT reads done

        // ---- Oproj: attended += O @ wo[24h:24h+24, :]  (+ stage next head) ----
        // chunk 4, b128 obuf broadcast + b128 transposed-weight loads
        #pragma unroll 1
        for (int d0 = 0; d0 < HD_; d0 += 4) {
            float4 ov4[NR5];
            #pragma unroll
            for (int i = 0; i < NR5; ++i)
                ov4[i] = *reinterpret_cast<const float4*>(&obuf[(rbase+i)*28 + d0]);
            float4 w4[3];
            #pragma unroll
            for (int j = 0; j < 3; ++j)
                w4[j] = *reinterpret_cast<const float4*>(&woT[(tc+32*j)*D_ + HD_*h + d0]);
            #pragma unroll
            for (int j = 0; j < 3; ++j)
                #pragma unroll
                for (int i = 0; i < NR5; ++i)
                    ao[j][i] += ov4[i].x*w4[j].x + ov4[i].y*w4[j].y
                              + ov4[i].z*w4[j].z + ov4[i].w*w4[j].w;
        }
        if (h < NH_-1) stage(h+1);      // writes qh/kh/vhT: disjoint from obuf reads
        __syncthreads();    // A(h+1): staged data visible before next scores
    }

    // ---- epilogue: attended -> LDS, imp softmax, node, LN ----
    #pragma unroll
    for (int j = 0; j < 3; ++j) {
        const int c = tc + 32*j;
        #pragma unroll
        for (int i = 0; i < NR5; ++i) ats[(rbase+i)*100 + c] = ao[j][i];
    }
    __syncthreads();

    if (tid < P_) {                         // row mean over D
        const float* ar = ats + tid*100;
        float s = 0.f;
        #pragma unroll 1
        for (int d = 0; d < D_; ++d) s += ar[d];
        rr[tid] = s*(1.0f/D_);
    }
    __syncthreads();
    if (tid < 64) {                         // imp = softmax over P (wave 0)
        const float a0 = rr[tid];
        const float a1 = (tid < 8) ? rr[64+tid] : -3.0e38f;
        float mx = fmaxf(a0, a1);
        #pragma unroll
        for (int s = 1; s < 64; s <<= 1) mx = fmaxf(mx, __shfl_xor(mx, s));
        const float e0 = __expf(a0-mx);
        const float e1 = (tid < 8) ? __expf(a1-mx) : 0.f;
        float sm = e0 + e1;
        #pragma unroll
        for (int s = 1; s < 64; s <<= 1) sm += __shfl_xor(sm, s);
        const float inv = 1.0f/sm;
        rr[tid] = e0*inv;
        if (tid < 8) rr[64+tid] = e1*inv;
    }
    __syncthreads();
    if (tid < D_) {
        float s = 0.f;
        #pragma unroll 1
        for (int i = 0; i < P_; ++i) s += ats[i*100+tid]*rr[i];
        nb[tid] = s + mpr;
    }
    __syncthreads();
    if (tid < 64) {                         // LN stats (wave 0)
        const float x0 = nb[tid];
        const float x1 = (tid < 32) ? nb[64+tid] : 0.f;
        float sm = x0 + x1;
        float sq = x0*x0 + x1*x1;
        #pragma unroll
        for (int s = 1; s < 64; s <<= 1) { sm += __shfl_xor(sm, s); sq += __shfl_xor(sq, s); }
        if (tid == 0) {
            const float m = sm*(1.0f/D_);
            const float v = sq*(1.0f/D_) - m*m;
            st2[0] = m; st2[1] = rsqrtf(v + 1e-5f);
        }
    }
    __syncthreads();
    if (tid < D_) {
        const float y = (nb[tid]-st2[0])*st2[1]*tng[tid] + tnb[tid];
        node_out[(size_t)bn*D_+tid] = y;
    }
}

// ---------------------------------------------------------------------------
// Kernel 2: h1 = gelu(LN(node @ de_w1 + b1))
// ---------------------------------------------------------------------------
__global__ __launch_bounds__(128) void enc1_kernel(
    const float* __restrict__ node, const float* __restrict__ w1, const float* __restrict__ b1,
    const float* __restrict__ g1, const float* __restrict__ be1, float* __restrict__ h1)
{
    __shared__ float nr[D_];
    __shared__ float buf[128];
    __shared__ float st2[2];
    const int tid = threadIdx.x; const int bn = blockIdx.x;
    if (tid < D_) nr[tid] = node[(size_t)bn*D_+tid];
    __syncthreads();
    float s = b1[tid];
    for (int c = 0; c < D_; ++c) s += nr[c]*w1[c*128+tid];
    buf[tid] = s;
    __syncthreads();
    if (tid == 0) {
        float m=0.f; for(int d=0;d<128;++d) m+=buf[d]; m *= (1.0f/128.0f);
        float v=0.f; for(int d=0;d<128;++d){ float df=buf[d]-m; v+=df*df; } v *= (1.0f/128.0f);
        st2[0]=m; st2[1]=rsqrtf(v+1e-5f);
    }
    __syncthreads();
    float y = (buf[tid]-st2[0])*st2[1]*g1[tid] + be1[tid];
    h1[(size_t)bn*128+tid] = gelu_f(y);
}

// ---------------------------------------------------------------------------
// Kernel 3: dyn = LN(h1 @ de_w2 + b2)
// ---------------------------------------------------------------------------
__global__ __launch_bounds__(64) void enc2_kernel(
    const float* __restrict__ h1, const float* __restrict__ w2, const float* __restrict__ b2,
    const float* __restrict__ g2, const float* __restrict__ be2, float* __restrict__ dyn)
{
    __shared__ float hr[128];
    __shared__ float buf[ND_];
    __shared__ float st2[2];
    const int tid = threadIdx.x; const int bn = blockIdx.x;
    hr[tid] = h1[(size_t)bn*128+tid];
    hr[tid+64] = h1[(size_t)bn*128+64+tid];
    __syncthreads();
    float s = b2[tid];
    for (int c = 0; c < 128; ++c) s += hr[c]*w2[c*ND_+tid];
    buf[tid] = s;
    __syncthreads();
    if (tid == 0) {
        float m=0.f; for(int d=0;d<ND_;++d) m+=buf[d]; m *= (1.0f/ND_);
        float v=0.f; for(int d=0;d<ND_;++d){ float df=buf[d]-m; v+=df*df; } v *= (1.0f/ND_);
        st2[0]=m; st2[1]=rsqrtf(v+1e-5f);
    }
    __syncthreads();
    dyn[(size_t)bn*ND_+tid] = (buf[tid]-st2[0])*st2[1]*g2[tid] + be2[tid];
}

// ---------------------------------------------------------------------------
// Kernel 4: one GNN layer (one block per (b,n) row)
// ---------------------------------------------------------------------------
__global__ __launch_bounds__(256) void gnn_kernel(
    const float* __restrict__ din, float* __restrict__ dout,
    const float* __restrict__ gw, const float* __restrict__ gb,
    const float* __restrict__ gg, const float* __restrict__ gbe, int layer)
{
    __shared__ float dq[ND_];
    __shared__ float prob[N_];
    __shared__ float red[256];
    __shared__ float aggp[4*ND_];
    __shared__ float buf[ND_];
    __shared__ float st2[2];
    const int tid = threadIdx.x; const int bn = blockIdx.x;
    const int b = bn / N_;
    const float* base = din + (size_t)b*N_*ND_;
    if (tid < ND_) dq[tid] = din[(size_t)bn*ND_+tid];
    __syncthreads();

    float lmax = -1e30f;
    for (int m = tid; m < N_; m += 256) {
        const float* rm = base + (size_t)m*ND_;
        float s = 0.f;
        for (int c = 0; c < ND_; ++c) s += dq[c]*rm[c];
        s *= 5.0f;                              // /0.2
        prob[m] = s;
        lmax = fmaxf(lmax, s);
    }
    red[tid]=lmax; __syncthreads();
    for (int st=128; st>0; st>>=1){ if(tid<st) red[tid]=fmaxf(red[tid],red[tid+st]); __syncthreads(); }
    const float mx = red[0]; __syncthreads();
    float lsum = 0.f;
    for (int m=tid; m<N_; m+=256){ float ev=expf(prob[m]-mx); prob[m]=ev; lsum+=ev; }
    red[tid]=lsum; __syncthreads();
    for (int st=128; st>0; st>>=1){ if(tid<st) red[tid]+=red[tid+st]; __syncthreads(); }
    const float inv = 1.0f/red[0]; __syncthreads();
    for (int m=tid; m<N_; m+=256) prob[m]*=inv;
    __syncthreads();

    {   // agg = sim @ dyn
        const int part = tid >> 6, d = tid & 63;
        float s = 0.f;
        for (int m = part; m < N_; m += 4) s += prob[m]*base[(size_t)m*ND_+d];
        aggp[part*ND_+d] = s;
    }
    __syncthreads();
    if (tid < ND_)
        aggp[tid] = aggp[tid]+aggp[ND_+tid]+aggp[2*ND_+tid]+aggp[3*ND_+tid];
    __syncthreads();
    if (tid < ND_) {
        float t = gb[layer*ND_+tid];
        for (int c = 0; c < ND_; ++c) t += aggp[c]*gw[(layer*ND_+c)*ND_+tid];
        buf[tid] = t;
    }
    __syncthreads();
    if (tid == 0) {
        float m=0.f; for(int d=0;d<ND_;++d) m+=buf[d]; m *= (1.0f/ND_);
        float v=0.f; for(int d=0;d<ND_;++d){ float df=buf[d]-m; v+=df*df; } v *= (1.0f/ND_);
        st2[0]=m; st2[1]=rsqrtf(v+1e-5f);
    }
    __syncthreads();
    if (tid < ND_) {
        float y = (buf[tid]-st2[0])*st2[1]*gg[layer*ND_+tid] + gbe[layer*ND_+tid];
        dout[(size_t)bn*ND_+tid] = gelu_f(y) + dq[tid];
    }
}

// ---------------------------------------------------------------------------
// Wave-per-row softmax + top-k + renormalize + store. No __syncthreads.
// lv[j] = relu'd, temperature-scaled logits at positions m = lane + 64*j.
// Tie-break: max value, lowest index (matches lax.top_k stability).
// ---------------------------------------------------------------------------
__device__ __forceinline__ void wave_softmax_topk_store(
    float lv[RPW_], int lane, float* __restrict__ outrow)
{
    float mx = 0.f;                     // logits >= 0 (post-relu), 0 is a valid floor
    #pragma unroll
    for (int j=0;j<RPW_;++j) mx = fmaxf(mx, lv[j]);
    #pragma unroll
    for (int s=1;s<64;s<<=1) mx = fmaxf(mx, __shfl_xor(mx, s));
    float sm = 0.f;
    #pragma unroll
    for (int j=0;j<RPW_;++j) {
        const int m = lane + 64*j;
        const float e = (m < N_) ? expf(lv[j]-mx) : 0.f;
        lv[j] = e; sm += e;
    }
    #pragma unroll
    for (int s=1;s<64;s<<=1) sm += __shfl_xor(sm, s);
    const float inv = 1.0f/sm;
    #pragma unroll
    for (int j=0;j<RPW_;++j) lv[j] *= inv;

    unsigned sel = 0u;
    float ksum = 0.f;
    for (int it = 0; it < K_; ++it) {
        float bv = -1.f; int bm = 0x7fffffff;
        #pragma unroll
        for (int j=0;j<RPW_;++j) {
            const int m = lane + 64*j;
            if (m < N_ && !((sel>>j)&1u) && lv[j] > bv) { bv = lv[j]; bm = m; }
        }
        #pragma unroll
        for (int s=1;s<64;s<<=1) {
            const float ov = __shfl_xor(bv, s);
            const int   om = __shfl_xor(bm, s);
            if (ov > bv || (ov == bv && om < bm)) { bv = ov; bm = om; }
        }
        ksum += bv;
        if ((bm & 63) == lane) sel |= 1u << (bm >> 6);
    }
    const float dn = 1.0f/(ksum + 1e-8f);
    #pragma unroll
    for (int j=0;j<RPW_;++j) {
        const int m = lane + 64*j;
        if (m < N_) outrow[m] = ((sel>>j)&1u) ? lv[j]*dn : 0.f;
    }
}

// ---------------------------------------------------------------------------
// Kernel 5: static adjacency — one WAVE per (h,n) row; 4 rows per block
// ---------------------------------------------------------------------------
__global__ __launch_bounds__(256) void static_adj_kernel(
    const float* __restrict__ le1, const float* __restrict__ le2,
    const float* __restrict__ ge1, const float* __restrict__ ge2,
    const float* __restrict__ temp, float* __restrict__ outs)
{
    __shared__ float e1l[4][ND_];
    const int tid = threadIdx.x;
    const int wv = tid >> 6, lane = tid & 63;
    const int r = blockIdx.x*4 + wv;        // r = h*N_ + n, grid = H_*N_/4
    const int h = r / N_, n = r % N_;
    if (h < 2) { if (lane < 32) e1l[wv][lane] = le1[(h*N_+n)*32+lane]; }
    else       { e1l[wv][lane] = ge1[((h-2)*N_+n)*64+lane]; }
    __syncthreads();
    const float t = temp[h];
    const float tl = (h < 2) ? fminf(fmaxf(t*2.0f,0.1f),5.0f) : fminf(fmaxf(t*0.5f,0.1f),2.0f);
    const float invt = 1.0f/tl;
    float lv[RPW_];
    #pragma unroll
    for (int j=0;j<RPW_;++j) lv[j] = 0.f;
    if (h < 2) {
        for (int c = 0; c < 32; ++c) {
            const float dc = e1l[wv][c];
            const float* sr = le2 + (size_t)(h*32+c)*N_;
            #pragma unroll
            for (int j=0;j<RPW_;++j) {
                const int m = lane + 64*j;
                if (m < N_) lv[j] += dc*sr[m];
            }
        }
    } else {
        for (int c = 0; c < 64; ++c) {
            const float dc = e1l[wv][c];
            const float* sr = ge2 + (size_t)((h-2)*64+c)*N_;
            #pragma unroll
            for (int j=0;j<RPW_;++j) {
                const int m = lane + 64*j;
                if (m < N_) lv[j] += dc*sr[m];
            }
        }
    }
    #pragma unroll
    for (int j=0;j<RPW_;++j) lv[j] = fmaxf(lv[j],0.f)*invt;
    wave_softmax_topk_store(lv, lane, outs + (size_t)r*N_);
}

// ---------------------------------------------------------------------------
// Kernel 6: dynamic adjacency — one WAVE per (b,h,n) row; 4 rows per block
// ---------------------------------------------------------------------------
__global__ __launch_bounds__(256) void dyn_adj_kernel(
    const float* __restrict__ dyn, const float* __restrict__ se2,
    const float* __restrict__ temp, float* __restrict__ outd)
{
    __shared__ float dql[4][ND_];
    const int tid = threadIdx.x;
    const int wv = tid >> 6, lane = tid & 63;
    const int r = blockIdx.x*4 + wv;        // grid = B_*H_*N_/4 = 5728
    const int b = r / (H_*N_);
    const int rem = r % (H_*N_);
    const int h = rem / N_, n = rem % N_;
    dql[wv][lane] = dyn[((size_t)(b*N_+n))*ND_ + lane];
    __syncthreads();
    const float invt = 1.0f/fminf(fmaxf(temp[h],0.1f),2.0f);
    float lv[RPW_];
    #pragma unroll
    for (int j=0;j<RPW_;++j) lv[j] = 0.f;
    const float* sb = se2 + (size_t)h*ND_*N_;
    for (int c = 0; c < ND_; ++c) {
        const float dc = dql[wv][c];
        const float* sr = sb + (size_t)c*N_;
        #pragma unroll
        for (int j=0;j<RPW_;++j) {
            const int m = lane + 64*j;
            if (m < N_) lv[j] += dc*sr[m];
        }
    }
    #pragma unroll
    for (int j=0;j<RPW_;++j) lv[j] = fmaxf(lv[j],0.f)*invt;
    wave_softmax_topk_store(lv, lane, outd + ((size_t)(b*H_+h)*N_+n)*(size_t)N_);
}

// ---------------------------------------------------------------------------
// Kernel 7: fusion gate  w = sigmoid(node_f @ gf_w + gf_b)
// ---------------------------------------------------------------------------
__global__ __launch_bounds__(256) void fw_kernel(
    const float* __restrict__ meanpr, const float* __restrict__ gfw,
    const float* __restrict__ gfb, float* __restrict__ wf)
{
    const int gid = blockIdx.x*256 + threadIdx.x;
    if (gid >= BN_*H_) return;
    const int bn = gid >> 2, h = gid & 3;
    float s = gfb[h];
    const float* mp = meanpr + (size_t)bn*D_;
    for (int c=0;c<D_;++c) s += mp[c]*gfw[c*H_+h];
    wf[gid] = sigm_f(s);
}

// ---------------------------------------------------------------------------
// Kernel 8: fusion + edge-encoder MLP + final (one thread per (b,n,m))
// ---------------------------------------------------------------------------
__global__ __launch_bounds__(256) void edge_kernel(
    const float* __restrict__ staticf, const float* __restrict__ dynf,
    const float* __restrict__ wf,
    const float* __restrict__ ew1, const float* __restrict__ eb1,
    const float* __restrict__ eg,  const float* __restrict__ ebe,
    const float* __restrict__ ew2, const float* __restrict__ eb2,
    const float* __restrict__ ew3, const float* __restrict__ eb3,
    float* __restrict__ outf)
{
    __shared__ float w1s[64], w2s[128], b1s[16], gs[16], bes[16], b2s[8], w3s[8];
    __shared__ float b3v;
    const int tid = threadIdx.x;
    if (tid < 64)                 w1s[tid]     = ew1[tid];
    else if (tid < 192)           w2s[tid-64]  = ew2[tid-64];
    else if (tid < 208)           b1s[tid-192] = eb1[tid-192];
    else if (tid < 224)           gs[tid-208]  = eg[tid-208];
    else if (tid < 240)           bes[tid-224] = ebe[tid-224];
    else if (tid < 248)           b2s[tid-240] = eb2[tid-240];
    else                          w3s[tid-248] = ew3[tid-248];
    if (tid == 0) b3v = eb3[0];
    __syncthreads();

    const size_t gid = (size_t)blockIdx.x*256 + tid;
    if (gid >= (size_t)B_*NN_) return;
    const int m = (int)(gid % N_);
    const size_t t1 = gid / N_;
    const int n = (int)(t1 % N_);
    const int b = (int)(t1 / N_);

    const float* wrow = wf + ((size_t)(b*N_+n))*4;
    float mh[4]; float msum = 0.f;
    #pragma unroll
    for (int h=0; h<4; ++h) {
        float w  = wrow[h];
        float st = staticf[((size_t)(h*N_+n))*N_ + m];
        float da = dynf[(((size_t)(b*4+h))*N_+n)*(size_t)N_ + m];
        float f = (1.0f-w)*st + w*da;
        mh[h] = f; msum += f;
    }
    float e16[16]; float mean = 0.f;
    #pragma unroll
    for (int j=0;j<16;++j) {
        float s = b1s[j];
        #pragma unroll
        for (int h=0;h<4;++h) s += mh[h]*w1s[h*16+j];
        e16[j] = s; mean += s;
    }
    mean *= (1.0f/16.0f);
    float var = 0.f;
    #pragma unroll
    for (int j=0;j<16;++j){ float df=e16[j]-mean; var += df*df; }
    var *= (1.0f/16.0f);
    const float rinv = rsqrtf(var + 1e-5f);
    #pragma unroll
    for (int j=0;j<16;++j) e16[j] = gelu_f((e16[j]-mean)*rinv*gs[j] + bes[j]);
    float e8[8];
    #pragma unroll
    for (int o=0;o<8;++o) {
        float s = b2s[o];
        #pragma unroll
        for (int j=0;j<16;++j) s += e16[j]*w2s[j*8+o];
        e8[o] = gelu_f(s);
    }
    float e = b3v;
    #pragma unroll
    for (int o=0;o<8;++o) e += e8[o]*w3s[o];
    outf[gid] = sigm_f(e) * (msum*0.25f);
}

// ---------------------------------------------------------------------------
extern "C" void kernel_launch(void* const* d_in, const int* in_sizes, int n_in,
                              void* d_out, int out_size, void* d_ws, size_t ws_size,
                              hipStream_t stream)
{
    const float* patch = (const float*)d_in[0];
    const float* le1   = (const float*)d_in[1];
    const float* le2   = (const float*)d_in[2];
    const float* ge1   = (const float*)d_in[3];
    const float* ge2   = (const float*)d_in[4];
    const float* se2   = (const float*)d_in[5];
    const float* temp  = (const float*)d_in[6];
    const float* pos   = (const float*)d_in[7];
    const float* wq    = (const float*)d_in[8];
    const float* bq    = (const float*)d_in[9];
    const float* wk    = (const float*)d_in[10];
    const float* bk    = (const float*)d_in[11];
    const float* wv    = (const float*)d_in[12];
    const float* bv    = (const float*)d_in[13];
    const float* wo    = (const float*)d_in[14];
    const float* bo    = (const float*)d_in[15];
    const float* tng   = (const float*)d_in[16];
    const float* tnb   = (const float*)d_in[17];
    const float* dw1   = (const float*)d_in[18];
    const float* db1   = (const float*)d_in[19];
    const float* dg1   = (const float*)d_in[20];
    const float* dbe1  = (const float*)d_in[21];
    const float* dw2   = (const float*)d_in[22];
    const float* db2   = (const float*)d_in[23];
    const float* dg2   = (const float*)d_in[24];
    const float* dbe2  = (const float*)d_in[25];
    const float* gw    = (const float*)d_in[26];
    const float* gb    = (const float*)d_in[27];
    const float* gg    = (const float*)d_in[28];
    const float* gbe   = (const float*)d_in[29];
    const float* gfw   = (const float*)d_in[30];
    const float* gfb   = (const float*)d_in[31];
    const float* ew1   = (const float*)d_in[32];
    const float* eb1   = (const float*)d_in[33];
    const float* eg    = (const float*)d_in[34];
    const float* ebe   = (const float*)d_in[35];
    const float* ew2   = (const float*)d_in[36];
    const float* eb2   = (const float*)d_in[37];
    const float* ew3   = (const float*)d_in[38];
    const float* eb3   = (const float*)d_in[39];
    (void)in_sizes; (void)n_in; (void)out_size; (void)ws_size;

    // workspace layout: BN*384 floats (8.8 MB) + 4*96*96 transposed weights
    float* ws      = (float*)d_ws;
    float* meanpr  = ws;                        // BN*96, live until fw_kernel
    float* node    = meanpr + (size_t)BN_*D_;   // BN*96; dead after enc1 -> reused as dyn1
    float* h1      = node   + (size_t)BN_*D_;   // BN*128; dead after enc2 -> reused as wfuse
    float* dyn0    = h1     + (size_t)BN_*128;  // BN*64
    float* dyn1    = node;                      // alias (gnn layer0 output)
    float* wfuse   = h1;                        // alias (BN*4)
    float* wqT     = dyn0   + (size_t)BN_*ND_;  // 9216 each
    float* wkT     = wqT + D_*D_;
    float* wvT     = wkT + D_*D_;
    float* woT     = wvT + D_*D_;

    float* out        = (float*)d_out;
    float* out_final  = out;
    float* out_static = out + (size_t)B_*NN_;
    float* out_dyn    = out_static + (size_t)H_*NN_;

    transw_kernel<<<(4*D_*D_+255)/256, 256, 0, stream>>>(wq,wk,wv,wo,wqT,wkT,wvT,woT);
    attn_kernel<<<BN_, 512, 0, stream>>>(patch,pos,wqT,bq,wkT,bk,wvT,bv,woT,bo,tng,tnb,node,meanpr);
    enc1_kernel<<<BN_, 128, 0, stream>>>(node,dw1,db1,dg1,dbe1,h1);
    enc2_kernel<<<BN_, 64,  0, stream>>>(h1,dw2,db2,dg2,dbe2,dyn0);
    gnn_kernel<<<BN_, 256, 0, stream>>>(dyn0,dyn1,gw,gb,gg,gbe,0);
    gnn_kernel<<<BN_, 256, 0, stream>>>(dyn1,dyn0,gw,gb,gg,gbe,1);
    static_adj_kernel<<<H_*N_/4, 256, 0, stream>>>(le1,le2,ge1,ge2,temp,out_static);
    dyn_adj_kernel<<<B_*H_*N_/4, 256, 0, stream>>>(dyn0,se2,temp,out_dyn);
    fw_kernel<<<(BN_*H_+255)/256, 256, 0, stream>>>(meanpr,gfw,gfb,wfuse);
    edge_kernel<<<((size_t)B_*NN_+255)/256, 256, 0, stream>>>(
        out_static,out_dyn,wfuse,ew1,eb1,eg,ebe,ew2,eb2,ew3,eb3,out_final);
}

// Round 6
// 2720.774 us; speedup vs baseline: 1.2936x; 1.2936x over previous
//
#include <hip/hip_runtime.h>
#include <hip/hip_bf16.h>

#define B_ 16
#define N_ 358
#define P_ 72
#define D_ 96
#define ND_ 64
#define H_ 4
#define NH_ 4
#define HD_ 24
#define K_ 10
#define BN_ (B_*N_)     /* 5728 */
#define NN_ (N_*N_)     /* 128164 */
#define RPW_ 6          /* ceil(358/64) elements per lane in wave-per-row kernels */
#define NR5 5           /* rows per 32-lane group in attn (16 groups x 5 = 80 padded rows) */

__device__ __forceinline__ float gelu_f(float x){ return 0.5f*x*(1.0f+erff(x*0.7071067811865476f)); }
__device__ __forceinline__ float sigm_f(float x){ return 1.0f/(1.0f+expf(-x)); }

// ---------------------------------------------------------------------------
// Kernel 0: pack weights k-chunked so attn weight loads are WIDE and
// COALESCED (R4 scar: [c][k] transposed layout gave lane-stride 384B ->
// uncoalesced b128 -> +22% regression. Fix: chunk k, keep c adjacent):
//   wqkv_p[k2][c][2]: c=0..287 (q|k|v concat), = w[2*k2+kk][c%96]
//     -> P1 lane reads dwordx2 at lane-stride 8B (contiguous).
//   wo_p[d4][c][4]: = wo[4*d4+kk][c]
//     -> Oproj lane reads dwordx4 at lane-stride 16B (contiguous).
// ---------------------------------------------------------------------------
__global__ __launch_bounds__(256) void packw_kernel(
    const float* __restrict__ wq, const float* __restrict__ wk,
    const float* __restrict__ wv, const float* __restrict__ wo,
    float* __restrict__ wqkv_p, float* __restrict__ wo_p)
{
    const int gid = blockIdx.x*256 + threadIdx.x;
    if (gid < 48*288) {                 // wqkv_p: 48 k2-chunks x 288 cols x 2
        const int k2 = gid / 288, c = gid % 288;
        const float* src = (c < 96) ? wq : (c < 192) ? wk : wv;
        const int cc = (c >= 192) ? c-192 : (c >= 96) ? c-96 : c;
        wqkv_p[gid*2+0] = src[(2*k2+0)*D_ + cc];
        wqkv_p[gid*2+1] = src[(2*k2+1)*D_ + cc];
    }
    if (gid < 24*96) {                  // wo_p: 24 d4-chunks x 96 cols x 4
        const int d4 = gid / 96, c = gid % 96;
        wo_p[gid*4+0] = wo[(4*d4+0)*D_ + c];
        wo_p[gid*4+1] = wo[(4*d4+1)*D_ + c];
        wo_p[gid*4+2] = wo[(4*d4+2)*D_ + c];
        wo_p[gid*4+3] = wo[(4*d4+3)*D_ + c];
    }
}

// ---------------------------------------------------------------------------
// Kernel 1: temporal attention + node embedding (one block per (b,n) sequence)
//
// LAUNCH-BOUNDS SCAR (R1): 2nd arg = min blocks/CU on this toolchain.
// (512,4) -> cap 64 -> 33GB spill. (512,2) -> 16 waves/CU, cap 128. KEEP.
// SPILL SCAR (R2): chunk-4 temps without unroll-1 overflowed cap 128.
// All hot loops carry "#pragma unroll 1".
// COALESCING SCAR (R4): [c][k] weight loads (lane-stride 384B) cost +22%.
// R5 uses packed layouts (see packw_kernel) -> wide AND coalesced.
//
// Proven-fit register shapes: combined P1 chunk-2 ~85 regs; scores chunk-4
// with kh b128 = R4's measured 104; Oproj chunk-4 ~92. All < 128.
// All dot products are nested fmaf chains (no reassoc-add bloat).
//
// LDS pool (floats): qh[80][28]=2240 @0 | kh[96][28]=2688 @2240 |
//  vhT[24][84]=2016 @4928 | att[80][76]=6080 @6944 | obuf[80][28]=2240 @13024
//  xs/ats [80][100]=8000 @0 (phase-ordered overlap). Total 15264 = 61.1KB.
//  kh rows 80..95 unwritten garbage, consumed only by masked lanes — safe.
//  Bank conflicts measured negligible (6.05M cyc/dispatch ~ 10us/CU).
// ---------------------------------------------------------------------------
__global__ __launch_bounds__(512, 2) void attn_kernel(
    const float* __restrict__ patch, const float* __restrict__ pos,
    const float* __restrict__ wqkv_p, const float* __restrict__ bq,
    const float* __restrict__ bk, const float* __restrict__ bv,
    const float* __restrict__ wo_p, const float* __restrict__ bo,
    const float* __restrict__ tng, const float* __restrict__ tnb,
    float* __restrict__ node_out, float* __restrict__ meanpr_out)
{
    __shared__ __align__(16) float pool[15264];
    __shared__ float rr[80];
    __shared__ float nb[D_];
    __shared__ float st2[2];

    float* const xs   = pool;           // [80][100] phase 1
    float* const qh   = pool;           // [80][28]
    float* const kh   = pool + 2240;    // [96][28]
    float* const vhT  = pool + 4928;    // [24][84]
    float* const att  = pool + 6944;    // [80][76]
    float* const obuf = pool + 13024;   // [80][28]
    float* const ats  = pool;           // [80][100] epilogue

    const int tid = threadIdx.x;
    const int tc  = tid & 31;
    const int tr  = tid >> 5;           // 0..15
    const int rbase = tr * NR5;         // 0,5,...,75
    const int bn  = blockIdx.x;
    const float* pr = patch + (size_t)bn * (P_*D_);

    // mean over P of pr (node_f) -- kept in a register by threads tid<96
    float mpr = 0.f;
    if (tid < D_) {
        #pragma unroll 1
        for (int p = 0; p < P_; ++p) mpr += pr[p*D_+tid];
        mpr *= (1.0f/P_);
        meanpr_out[(size_t)bn*D_ + tid] = mpr;
    }

    // load X = pr + pos into LDS [80][100]; rows 72..79 and cols 96..99 zero
    #pragma unroll 1
    for (int e = tid; e < 80*100; e += 512) {
        const int row = e / 100, col = e - row*100;
        xs[e] = (row < P_ && col < D_) ? (pr[row*D_+col] + pos[row*D_+col]) : 0.f;
    }
    __syncthreads();

    // ---- phase 1: Q,K,V = X @ W + b. SINGLE pass over k (xs read once),
    //      chunk-2, packed dwordx2 weight loads (coalesced). ~85 regs. ----
    float aq[3][NR5], ak[3][NR5], av[3][NR5];
    #pragma unroll
    for (int j = 0; j < 3; ++j) {
        const int c = tc + 32*j;
        const float vbq = bq[c], vbk = bk[c], vbv = bv[c];
        #pragma unroll
        for (int i = 0; i < NR5; ++i) { aq[j][i]=vbq; ak[j][i]=vbk; av[j][i]=vbv; }
    }
    {
        const float* wp = wqkv_p + (size_t)tc*2;    // + k2*576 per iter
        #pragma unroll 1
        for (int k2 = 0; k2 < 48; ++k2) {
            float2 xv[NR5];
            #pragma unroll
            for (int i = 0; i < NR5; ++i)
                xv[i] = *reinterpret_cast<const float2*>(&xs[(rbase+i)*100 + 2*k2]);
            float2 wq2[3], wk2[3], wv2[3];
            const float* wpk = wp + (size_t)k2*576;
            #pragma unroll
            for (int j = 0; j < 3; ++j) {
                wq2[j] = *reinterpret_cast<const float2*>(&wpk[(32*j)*2]);
                wk2[j] = *reinterpret_cast<const float2*>(&wpk[(96+32*j)*2]);
                wv2[j] = *reinterpret_cast<const float2*>(&wpk[(192+32*j)*2]);
            }
            #pragma unroll
            for (int j = 0; j < 3; ++j)
                #pragma unroll
                for (int i = 0; i < NR5; ++i) {
                    aq[j][i] = fmaf(xv[i].x, wq2[j].x, fmaf(xv[i].y, wq2[j].y, aq[j][i]));
                    ak[j][i] = fmaf(xv[i].x, wk2[j].x, fmaf(xv[i].y, wk2[j].y, ak[j][i]));
                    av[j][i] = fmaf(xv[i].x, wv2[j].x, fmaf(xv[i].y, wv2[j].y, av[j][i]));
                }
        }
    }
    __syncthreads();        // all xs reads done; pool free for head buffers

    const float rs = 0.20412414523193154f;      // 1/sqrt(24)

    // attended accumulators (output of o @ wo + bo), live across heads
    float ao[3][NR5];
    #pragma unroll
    for (int j = 0; j < 3; ++j) {
        const float vbo = bo[tc + 32*j];
        #pragma unroll
        for (int i = 0; i < NR5; ++i) ao[j][i] = vbo;
    }

    // stage head hh's Q (pre-scaled by rs), K, V^T slices from registers
    auto stage = [&](int hh) {
        #pragma unroll
        for (int j = 0; j < 3; ++j) {
            const int c = tc + 32*j;
            const int dl = c - HD_*hh;
            if ((unsigned)dl < (unsigned)HD_) {
                #pragma unroll
                for (int i = 0; i < NR5; ++i) {
                    const int row = rbase + i;
                    qh [row*28 + dl] = aq[j][i] * rs;
                    kh [row*28 + dl] = ak[j][i];
                    vhT[dl*84 + row] = av[j][i];
                }
            }
        }
    };

    stage(0);
    __syncthreads();    // A0: head-0 qh/kh/vhT visible

    #pragma unroll 1
    for (int h = 0; h < NH_; ++h) {
        // ---- scores S = (Q*rs) K^T (chunk-4, b128 both sides; R4-proven) ----
        float sc[3][NR5];
        #pragma unroll
        for (int j = 0; j < 3; ++j)
            #pragma unroll
            for (int i = 0; i < NR5; ++i) sc[j][i] = 0.f;
        #pragma unroll 1
        for (int d0 = 0; d0 < HD_; d0 += 4) {
            float4 qv[NR5];
            #pragma unroll
            for (int i = 0; i < NR5; ++i)
                qv[i] = *reinterpret_cast<const float4*>(&qh[(rbase+i)*28 + d0]);
            float4 kv[3];
            #pragma unroll
            for (int j = 0; j < 3; ++j) {
                const int jn = tc + 32*j;       // <=95 < 96 rows of kh
                kv[j] = *reinterpret_cast<const float4*>(&kh[jn*28 + d0]);
            }
            #pragma unroll
            for (int j = 0; j < 3; ++j)
                #pragma unroll
                for (int i = 0; i < NR5; ++i)
                    sc[j][i] = fmaf(qv[i].x, kv[j].x,
                               fmaf(qv[i].y, kv[j].y,
                               fmaf(qv[i].z, kv[j].z,
                               fmaf(qv[i].w, kv[j].w, sc[j][i]))));
        }

        // ---- in-register row softmax (row owned by one 32-lane group) ----
        #pragma unroll
        for (int i = 0; i < NR5; ++i) {
            float m = fmaxf(sc[0][i], sc[1][i]);
            if (tc < 8) m = fmaxf(m, sc[2][i]);         // jn=64+tc valid iff tc<8
            #pragma unroll
            for (int s = 1; s < 32; s <<= 1) m = fmaxf(m, __shfl_xor(m, s, 32));
            const float e0 = __expf(sc[0][i]-m);
            const float e1 = __expf(sc[1][i]-m);
            const float e2 = (tc < 8) ? __expf(sc[2][i]-m) : 0.f;
            float sm = e0 + e1 + e2;
            #pragma unroll
            for (int s = 1; s < 32; s <<= 1) sm += __shfl_xor(sm, s, 32);
            const float inv = 1.0f/sm;
            const int row = rbase + i;
            att[row*76 + tc]      = e0*inv;
            att[row*76 + tc + 32] = e1*inv;
            if (tc < 8) att[row*76 + tc + 64] = e2*inv;
        }
        __syncthreads();    // B: P visible; qh/kh reads done

        // ---- PV: O[row][tc] = sum_j P[row][j] V[j][tc]  (tc < 24) ----
        if (tc < HD_) {
            float ov[NR5];
            #pragma unroll
            for (int i = 0; i < NR5; ++i) ov[i] = 0.f;
            #pragma unroll 1
            for (int j0 = 0; j0 < P_; j0 += 4) {
                const float4 vv = *reinterpret_cast<const float4*>(&vhT[tc*84 + j0]);
                #pragma unroll
                for (int i = 0; i < NR5; ++i) {
                    const float4 pa = *reinterpret_cast<const float4*>(&att[(rbase+i)*76 + j0]);
                    ov[i] = fmaf(pa.x, vv.x,
                            fmaf(pa.y, vv.y,
                            fmaf(pa.z, vv.z,
                            fmaf(pa.w, vv.w, ov[i]))));
                }
            }
            #pragma unroll
            for (int i = 0; i < NR5; ++i) obuf[(rbase+i)*28 + tc] = ov[i];
        }
        __syncthreads();    // C: O visible; att/vhT reads done

        // ---- Oproj: attended += O @ wo[24h..24h+23, :]; packed dwordx4
        //      coalesced weight loads; chunk-4 (~92 regs) ----
        #pragma unroll 1
        for (int d4 = 6*h; d4 < 6*h+6; ++d4) {
            float4 ov4[NR5];
            #pragma unroll
            for (int i = 0; i < NR5; ++i)
                ov4[i] = *reinterpret_cast<const float4*>(&obuf[(rbase+i)*28 + (d4-6*h)*4]);
            float4 w4[3];
            #pragma unroll
            for (int j = 0; j < 3; ++j)
                w4[j] = *reinterpret_cast<const float4*>(&wo_p[(d4*96 + tc+32*j)*4]);
            #pragma unroll
            for (int j = 0; j < 3; ++j)
                #pragma unroll
                for (int i = 0; i < NR5; ++i)
                    ao[j][i] = fmaf(ov4[i].x, w4[j].x,
                               fmaf(ov4[i].y, w4[j].y,
                               fmaf(ov4[i].z, w4[j].z,
                               fmaf(ov4[i].w, w4[j].w, ao[j][i]))));
        }
        if (h < NH_-1) stage(h+1);      // writes qh/kh/vhT: disjoint from obuf reads
        __syncthreads();    // A(h+1): staged data visible before next scores
    }

    // ---- epilogue: attended -> LDS, imp softmax, node, LN ----
    #pragma unroll
    for (int j = 0; j < 3; ++j) {
        const int c = tc + 32*j;
        #pragma unroll
        for (int i = 0; i < NR5; ++i) ats[(rbase+i)*100 + c] = ao[j][i];
    }
    __syncthreads();

    if (tid < P_) {                         // row mean over D
        const float* ar = ats + tid*100;
        float s = 0.f;
        #pragma unroll 1
        for (int d = 0; d < D_; ++d) s += ar[d];
        rr[tid] = s*(1.0f/D_);
    }
    __syncthreads();
    if (tid < 64) {                         // imp = softmax over P (wave 0)
        const float a0 = rr[tid];
        const float a1 = (tid < 8) ? rr[64+tid] : -3.0e38f;
        float mx = fmaxf(a0, a1);
        #pragma unroll
        for (int s = 1; s < 64; s <<= 1) mx = fmaxf(mx, __shfl_xor(mx, s));
        const float e0 = __expf(a0-mx);
        const float e1 = (tid < 8) ? __expf(a1-mx) : 0.f;
        float sm = e0 + e1;
        #pragma unroll
        for (int s = 1; s < 64; s <<= 1) sm += __shfl_xor(sm, s);
        const float inv = 1.0f/sm;
        rr[tid] = e0*inv;
        if (tid < 8) rr[64+tid] = e1*inv;
    }
    __syncthreads();
    if (tid < D_) {
        float s = 0.f;
        #pragma unroll 1
        for (int i = 0; i < P_; ++i) s += ats[i*100+tid]*rr[i];
        nb[tid] = s + mpr;
    }
    __syncthreads();
    if (tid < 64) {                         // LN stats (wave 0)
        const float x0 = nb[tid];
        const float x1 = (tid < 32) ? nb[64+tid] : 0.f;
        float sm = x0 + x1;
        float sq = x0*x0 + x1*x1;
        #pragma unroll
        for (int s = 1; s < 64; s <<= 1) { sm += __shfl_xor(sm, s); sq += __shfl_xor(sq, s); }
        if (tid == 0) {
            const float m = sm*(1.0f/D_);
            const float v = sq*(1.0f/D_) - m*m;
            st2[0] = m; st2[1] = rsqrtf(v + 1e-5f);
        }
    }
    __syncthreads();
    if (tid < D_) {
        const float y = (nb[tid]-st2[0])*st2[1]*tng[tid] + tnb[tid];
        node_out[(size_t)bn*D_+tid] = y;
    }
}

// ---------------------------------------------------------------------------
// Kernel 2: h1 = gelu(LN(node @ de_w1 + b1))
// ---------------------------------------------------------------------------
__global__ __launch_bounds__(128) void enc1_kernel(
    const float* __restrict__ node, const float* __restrict__ w1, const float* __restrict__ b1,
    const float* __restrict__ g1, const float* __restrict__ be1, float* __restrict__ h1)
{
    __shared__ float nr[D_];
    __shared__ float buf[128];
    __shared__ float st2[2];
    const int tid = threadIdx.x; const int bn = blockIdx.x;
    if (tid < D_) nr[tid] = node[(size_t)bn*D_+tid];
    __syncthreads();
    float s = b1[tid];
    for (int c = 0; c < D_; ++c) s += nr[c]*w1[c*128+tid];
    buf[tid] = s;
    __syncthreads();
    if (tid == 0) {
        float m=0.f; for(int d=0;d<128;++d) m+=buf[d]; m *= (1.0f/128.0f);
        float v=0.f; for(int d=0;d<128;++d){ float df=buf[d]-m; v+=df*df; } v *= (1.0f/128.0f);
        st2[0]=m; st2[1]=rsqrtf(v+1e-5f);
    }
    __syncthreads();
    float y = (buf[tid]-st2[0])*st2[1]*g1[tid] + be1[tid];
    h1[(size_t)bn*128+tid] = gelu_f(y);
}

// ---------------------------------------------------------------------------
// Kernel 3: dyn = LN(h1 @ de_w2 + b2)
// ---------------------------------------------------------------------------
__global__ __launch_bounds__(64) void enc2_kernel(
    const float* __restrict__ h1, const float* __restrict__ w2, const float* __restrict__ b2,
    const float* __restrict__ g2, const float* __restrict__ be2, float* __restrict__ dyn)
{
    __shared__ float hr[128];
    __shared__ float buf[ND_];
    __shared__ float st2[2];
    const int tid = threadIdx.x; const int bn = blockIdx.x;
    hr[tid] = h1[(size_t)bn*128+tid];
    hr[tid+64] = h1[(size_t)bn*128+64+tid];
    __syncthreads();
    float s = b2[tid];
    for (int c = 0; c < 128; ++c) s += hr[c]*w2[c*ND_+tid];
    buf[tid] = s;
    __syncthreads();
    if (tid == 0) {
        float m=0.f; for(int d=0;d<ND_;++d) m+=buf[d]; m *= (1.0f/ND_);
        float v=0.f; for(int d=0;d<ND_;++d){ float df=buf[d]-m; v+=df*df; } v *= (1.0f/ND_);
        st2[0]=m; st2[1]=rsqrtf(v+1e-5f);
    }
    __syncthreads();
    dyn[(size_t)bn*ND_+tid] = (buf[tid]-st2[0])*st2[1]*g2[tid] + be2[tid];
}

// ---------------------------------------------------------------------------
// Kernel 4: one GNN layer (one block per (b,n) row)
// ---------------------------------------------------------------------------
__global__ __launch_bounds__(256) void gnn_kernel(
    const float* __restrict__ din, float* __restrict__ dout,
    const float* __restrict__ gw, const float* __restrict__ gb,
    const float* __restrict__ gg, const float* __restrict__ gbe, int layer)
{
    __shared__ float dq[ND_];
    __shared__ float prob[N_];
    __shared__ float red[256];
    __shared__ float aggp[4*ND_];
    __shared__ float buf[ND_];
    __shared__ float st2[2];
    const int tid = threadIdx.x; const int bn = blockIdx.x;
    const int b = bn / N_;
    const float* base = din + (size_t)b*N_*ND_;
    if (tid < ND_) dq[tid] = din[(size_t)bn*ND_+tid];
    __syncthreads();

    float lmax = -1e30f;
    for (int m = tid; m < N_; m += 256) {
        const float* rm = base + (size_t)m*ND_;
        float s = 0.f;
        for (int c = 0; c < ND_; ++c) s += dq[c]*rm[c];
        s *= 5.0f;                              // /0.2
        prob[m] = s;
        lmax = fmaxf(lmax, s);
    }
    red[tid]=lmax; __syncthreads();
    for (int st=128; st>0; st>>=1){ if(tid<st) red[tid]=fmaxf(red[tid],red[tid+st]); __syncthreads(); }
    const float mx = red[0]; __syncthreads();
    float lsum = 0.f;
    for (int m=tid; m<N_; m+=256){ float ev=expf(prob[m]-mx); prob[m]=ev; lsum+=ev; }
    red[tid]=lsum; __syncthreads();
    for (int st=128; st>0; st>>=1){ if(tid<st) red[tid]+=red[tid+st]; __syncthreads(); }
    const float inv = 1.0f/red[0]; __syncthreads();
    for (int m=tid; m<N_; m+=256) prob[m]*=inv;
    __syncthreads();

    {   // agg = sim @ dyn
        const int part = tid >> 6, d = tid & 63;
        float s = 0.f;
        for (int m = part; m < N_; m += 4) s += prob[m]*base[(size_t)m*ND_+d];
        aggp[part*ND_+d] = s;
    }
    __syncthreads();
    if (tid < ND_)
        aggp[tid] = aggp[tid]+aggp[ND_+tid]+aggp[2*ND_+tid]+aggp[3*ND_+tid];
    __syncthreads();
    if (tid < ND_) {
        float t = gb[layer*ND_+tid];
        for (int c = 0; c < ND_; ++c) t += aggp[c]*gw[(layer*ND_+c)*ND_+tid];
        buf[tid] = t;
    }
    __syncthreads();
    if (tid == 0) {
        float m=0.f; for(int d=0;d<ND_;++d) m+=buf[d]; m *= (1.0f/ND_);
        float v=0.f; for(int d=0;d<ND_;++d){ float df=buf[d]-m; v+=df*df; } v *= (1.0f/ND_);
        st2[0]=m; st2[1]=rsqrtf(v+1e-5f);
    }
    __syncthreads();
    if (tid < ND_) {
        float y = (buf[tid]-st2[0])*st2[1]*gg[layer*ND_+tid] + gbe[layer*ND_+tid];
        dout[(size_t)bn*ND_+tid] = gelu_f(y) + dq[tid];
    }
}

// ---------------------------------------------------------------------------
// Wave-per-row softmax + top-k + renormalize + store. No __syncthreads.
// lv[j] = relu'd, temperature-scaled logits at positions m = lane + 64*j.
// Tie-break: max value, lowest index (matches lax.top_k stability).
// ---------------------------------------------------------------------------
__device__ __forceinline__ void wave_softmax_topk_store(
    float lv[RPW_], int lane, float* __restrict__ outrow)
{
    float mx = 0.f;                     // logits >= 0 (post-relu), 0 is a valid floor
    #pragma unroll
    for (int j=0;j<RPW_;++j) mx = fmaxf(mx, lv[j]);
    #pragma unroll
    for (int s=1;s<64;s<<=1) mx = fmaxf(mx, __shfl_xor(mx, s));
    float sm = 0.f;
    #pragma unroll
    for (int j=0;j<RPW_;++j) {
        const int m = lane + 64*j;
        const float e = (m < N_) ? expf(lv[j]-mx) : 0.f;
        lv[j] = e; sm += e;
    }
    #pragma unroll
    for (int s=1;s<64;s<<=1) sm += __shfl_xor(sm, s);
    const float inv = 1.0f/sm;
    #pragma unroll
    for (int j=0;j<RPW_;++j) lv[j] *= inv;

    unsigned sel = 0u;
    float ksum = 0.f;
    for (int it = 0; it < K_; ++it) {
        float bv = -1.f; int bm = 0x7fffffff;
        #pragma unroll
        for (int j=0;j<RPW_;++j) {
            const int m = lane + 64*j;
            if (m < N_ && !((sel>>j)&1u) && lv[j] > bv) { bv = lv[j]; bm = m; }
        }
        #pragma unroll
        for (int s=1;s<64;s<<=1) {
            const float ov = __shfl_xor(bv, s);
            const int   om = __shfl_xor(bm, s);
            if (ov > bv || (ov == bv && om < bm)) { bv = ov; bm = om; }
        }
        ksum += bv;
        if ((bm & 63) == lane) sel |= 1u << (bm >> 6);
    }
    const float dn = 1.0f/(ksum + 1e-8f);
    #pragma unroll
    for (int j=0;j<RPW_;++j) {
        const int m = lane + 64*j;
        if (m < N_) outrow[m] = ((sel>>j)&1u) ? lv[j]*dn : 0.f;
    }
}

// ---------------------------------------------------------------------------
// Kernel 5: static adjacency — one WAVE per (h,n) row; 4 rows per block
// ---------------------------------------------------------------------------
__global__ __launch_bounds__(256) void static_adj_kernel(
    const float* __restrict__ le1, const float* __restrict__ le2,
    const float* __restrict__ ge1, const float* __restrict__ ge2,
    const float* __restrict__ temp, float* __restrict__ outs)
{
    __shared__ float e1l[4][ND_];
    const int tid = threadIdx.x;
    const int wv = tid >> 6, lane = tid & 63;
    const int r = blockIdx.x*4 + wv;        // r = h*N_ + n, grid = H_*N_/4
    const int h = r / N_, n = r % N_;
    if (h < 2) { if (lane < 32) e1l[wv][lane] = le1[(h*N_+n)*32+lane]; }
    else       { e1l[wv][lane] = ge1[((h-2)*N_+n)*64+lane]; }
    __syncthreads();
    const float t = temp[h];
    const float tl = (h < 2) ? fminf(fmaxf(t*2.0f,0.1f),5.0f) : fminf(fmaxf(t*0.5f,0.1f),2.0f);
    const float invt = 1.0f/tl;
    float lv[RPW_];
    #pragma unroll
    for (int j=0;j<RPW_;++j) lv[j] = 0.f;
    if (h < 2) {
        for (int c = 0; c < 32; ++c) {
            const float dc = e1l[wv][c];
            const float* sr = le2 + (size_t)(h*32+c)*N_;
            #pragma unroll
            for (int j=0;j<RPW_;++j) {
                const int m = lane + 64*j;
                if (m < N_) lv[j] += dc*sr[m];
            }
        }
    } else {
        for (int c = 0; c < 64; ++c) {
            const float dc = e1l[wv][c];
            const float* sr = ge2 + (size_t)((h-2)*64+c)*N_;
            #pragma unroll
            for (int j=0;j<RPW_;++j) {
                const int m = lane + 64*j;
                if (m < N_) lv[j] += dc*sr[m];
            }
        }
    }
    #pragma unroll
    for (int j=0;j<RPW_;++j) lv[j] = fmaxf(lv[j],0.f)*invt;
    wave_softmax_topk_store(lv, lane, outs + (size_t)r*N_);
}

// ---------------------------------------------------------------------------
// Kernel 6: dynamic adjacency — one WAVE per (b,h,n) row; 4 rows per block
// ---------------------------------------------------------------------------
__global__ __launch_bounds__(256) void dyn_adj_kernel(
    const float* __restrict__ dyn, const float* __restrict__ se2,
    const float* __restrict__ temp, float* __restrict__ outd)
{
    __shared__ float dql[4][ND_];
    const int tid = threadIdx.x;
    const int wv = tid >> 6, lane = tid & 63;
    const int r = blockIdx.x*4 + wv;        // grid = B_*H_*N_/4 = 5728
    const int b = r / (H_*N_);
    const int rem = r % (H_*N_);
    const int h = rem / N_, n = rem % N_;
    dql[wv][lane] = dyn[((size_t)(b*N_+n))*ND_ + lane];
    __syncthreads();
    const float invt = 1.0f/fminf(fmaxf(temp[h],0.1f),2.0f);
    float lv[RPW_];
    #pragma unroll
    for (int j=0;j<RPW_;++j) lv[j] = 0.f;
    const float* sb = se2 + (size_t)h*ND_*N_;
    for (int c = 0; c < ND_; ++c) {
        const float dc = dql[wv][c];
        const float* sr = sb + (size_t)c*N_;
        #pragma unroll
        for (int j=0;j<RPW_;++j) {
            const int m = lane + 64*j;
            if (m < N_) lv[j] += dc*sr[m];
        }
    }
    #pragma unroll
    for (int j=0;j<RPW_;++j) lv[j] = fmaxf(lv[j],0.f)*invt;
    wave_softmax_topk_store(lv, lane, outd + ((size_t)(b*H_+h)*N_+n)*(size_t)N_);
}

// ---------------------------------------------------------------------------
// Kernel 7: fusion gate  w = sigmoid(node_f @ gf_w + gf_b)
// ---------------------------------------------------------------------------
__global__ __launch_bounds__(256) void fw_kernel(
    const float* __restrict__ meanpr, const float* __restrict__ gfw,
    const float* __restrict__ gfb, float* __restrict__ wf)
{
    const int gid = blockIdx.x*256 + threadIdx.x;
    if (gid >= BN_*H_) return;
    const int bn = gid >> 2, h = gid & 3;
    float s = gfb[h];
    const float* mp = meanpr + (size_t)bn*D_;
    for (int c=0;c<D_;++c) s += mp[c]*gfw[c*H_+h];
    wf[gid] = sigm_f(s);
}

// ---------------------------------------------------------------------------
// Kernel 8: fusion + edge-encoder MLP + final (one thread per (b,n,m))
// ---------------------------------------------------------------------------
__global__ __launch_bounds__(256) void edge_kernel(
    const float* __restrict__ staticf, const float* __restrict__ dynf,
    const float* __restrict__ wf,
    const float* __restrict__ ew1, const float* __restrict__ eb1,
    const float* __restrict__ eg,  const float* __restrict__ ebe,
    const float* __restrict__ ew2, const float* __restrict__ eb2,
    const float* __restrict__ ew3, const float* __restrict__ eb3,
    float* __restrict__ outf)
{
    __shared__ float w1s[64], w2s[128], b1s[16], gs[16], bes[16], b2s[8], w3s[8];
    __shared__ float b3v;
    const int tid = threadIdx.x;
    if (tid < 64)                 w1s[tid]     = ew1[tid];
    else if (tid < 192)           w2s[tid-64]  = ew2[tid-64];
    else if (tid < 208)           b1s[tid-192] = eb1[tid-192];
    else if (tid < 224)           gs[tid-208]  = eg[tid-208];
    else if (tid < 240)           bes[tid-224] = ebe[tid-224];
    else if (tid < 248)           b2s[tid-240] = eb2[tid-240];
    else                          w3s[tid-248] = ew3[tid-248];
    if (tid == 0) b3v = eb3[0];
    __syncthreads();

    const size_t gid = (size_t)blockIdx.x*256 + tid;
    if (gid >= (size_t)B_*NN_) return;
    const int m = (int)(gid % N_);
    const size_t t1 = gid / N_;
    const int n = (int)(t1 % N_);
    const int b = (int)(t1 / N_);

    const float* wrow = wf + ((size_t)(b*N_+n))*4;
    float mh[4]; float msum = 0.f;
    #pragma unroll
    for (int h=0; h<4; ++h) {
        float w  = wrow[h];
        float st = staticf[((size_t)(h*N_+n))*N_ + m];
        float da = dynf[(((size_t)(b*4+h))*N_+n)*(size_t)N_ + m];
        float f = (1.0f-w)*st + w*da;
        mh[h] = f; msum += f;
    }
    float e16[16]; float mean = 0.f;
    #pragma unroll
    for (int j=0;j<16;++j) {
        float s = b1s[j];
        #pragma unroll
        for (int h=0;h<4;++h) s += mh[h]*w1s[h*16+j];
        e16[j] = s; mean += s;
    }
    mean *= (1.0f/16.0f);
    float var = 0.f;
    #pragma unroll
    for (int j=0;j<16;++j){ float df=e16[j]-mean; var += df*df; }
    var *= (1.0f/16.0f);
    const float rinv = rsqrtf(var + 1e-5f);
    #pragma unroll
    for (int j=0;j<16;++j) e16[j] = gelu_f((e16[j]-mean)*rinv*gs[j] + bes[j]);
    float e8[8];
    #pragma unroll
    for (int o=0;o<8;++o) {
        float s = b2s[o];
        #pragma unroll
        for (int j=0;j<16;++j) s += e16[j]*w2s[j*8+o];
        e8[o] = gelu_f(s);
    }
    float e = b3v;
    #pragma unroll
    for (int o=0;o<8;++o) e += e8[o]*w3s[o];
    outf[gid] = sigm_f(e) * (msum*0.25f);
}

// ---------------------------------------------------------------------------
extern "C" void kernel_launch(void* const* d_in, const int* in_sizes, int n_in,
                              void* d_out, int out_size, void* d_ws, size_t ws_size,
                              hipStream_t stream)
{
    const float* patch = (const float*)d_in[0];
    const float* le1   = (const float*)d_in[1];
    const float* le2   = (const float*)d_in[2];
    const float* ge1   = (const float*)d_in[3];
    const float* ge2   = (const float*)d_in[4];
    const float* se2   = (const float*)d_in[5];
    const float* temp  = (const float*)d_in[6];
    const float* pos   = (const float*)d_in[7];
    const float* wq    = (const float*)d_in[8];
    const float* bq    = (const float*)d_in[9];
    const float* wk    = (const float*)d_in[10];
    const float* bk    = (const float*)d_in[11];
    const float* wv    = (const float*)d_in[12];
    const float* bv    = (const float*)d_in[13];
    const float* wo    = (const float*)d_in[14];
    const float* bo    = (const float*)d_in[15];
    const float* tng   = (const float*)d_in[16];
    const float* tnb   = (const float*)d_in[17];
    const float* dw1   = (const float*)d_in[18];
    const float* db1   = (const float*)d_in[19];
    const float* dg1   = (const float*)d_in[20];
    const float* dbe1  = (const float*)d_in[21];
    const float* dw2   = (const float*)d_in[22];
    const float* db2   = (const float*)d_in[23];
    const float* dg2   = (const float*)d_in[24];
    const float* dbe2  = (const float*)d_in[25];
    const float* gw    = (const float*)d_in[26];
    const float* gb    = (const float*)d_in[27];
    const float* gg    = (const float*)d_in[28];
    const float* gbe   = (const float*)d_in[29];
    const float* gfw   = (const float*)d_in[30];
    const float* gfb   = (const float*)d_in[31];
    const float* ew1   = (const float*)d_in[32];
    const float* eb1   = (const float*)d_in[33];
    const float* eg    = (const float*)d_in[34];
    const float* ebe   = (const float*)d_in[35];
    const float* ew2   = (const float*)d_in[36];
    const float* eb2   = (const float*)d_in[37];
    const float* ew3   = (const float*)d_in[38];
    const float* eb3   = (const float*)d_in[39];
    (void)in_sizes; (void)n_in; (void)out_size; (void)ws_size;

    // workspace layout: BN*384 floats (8.8 MB) + packed weights
    float* ws      = (float*)d_ws;
    float* meanpr  = ws;                        // BN*96, live until fw_kernel
    float* node    = meanpr + (size_t)BN_*D_;   // BN*96; dead after enc1 -> reused as dyn1
    float* h1      = node   + (size_t)BN_*D_;   // BN*128; dead after enc2 -> reused as wfuse
    float* dyn0    = h1     + (size_t)BN_*128;  // BN*64
    float* dyn1    = node;                      // alias (gnn layer0 output)
    float* wfuse   = h1;                        // alias (BN*4)
    float* wqkv_p  = dyn0   + (size_t)BN_*ND_;  // 48*288*2 = 27648
    float* wo_p    = wqkv_p + 48*288*2;         // 24*96*4  = 9216

    float* out        = (float*)d_out;
    float* out_final  = out;
    float* out_static = out + (size_t)B_*NN_;
    float* out_dyn    = out_static + (size_t)H_*NN_;

    packw_kernel<<<(48*288+255)/256, 256, 0, stream>>>(wq,wk,wv,wo,wqkv_p,wo_p);
    attn_kernel<<<BN_, 512, 0, stream>>>(patch,pos,wqkv_p,bq,bk,bv,wo_p,bo,tng,tnb,node,meanpr);
    enc1_kernel<<<BN_, 128, 0, stream>>>(node,dw1,db1,dg1,dbe1,h1);
    enc2_kernel<<<BN_, 64,  0, stream>>>(h1,dw2,db2,dg2,dbe2,dyn0);
    gnn_kernel<<<BN_, 256, 0, stream>>>(dyn0,dyn1,gw,gb,gg,gbe,0);
    gnn_kernel<<<BN_, 256, 0, stream>>>(dyn1,dyn0,gw,gb,gg,gbe,1);
    static_adj_kernel<<<H_*N_/4, 256, 0, stream>>>(le1,le2,ge1,ge2,temp,out_static);
    dyn_adj_kernel<<<B_*H_*N_/4, 256, 0, stream>>>(dyn0,se2,temp,out_dyn);
    fw_kernel<<<(BN_*H_+255)/256, 256, 0, stream>>>(meanpr,gfw,gfb,wfuse);
    edge_kernel<<<((size_t)B_*NN_+255)/256, 256, 0, stream>>>(
        out_static,out_dyn,wfuse,ew1,eb1,eg,ebe,ew2,eb2,ew3,eb3,out_final);
}

// Round 7
// 2701.829 us; speedup vs baseline: 1.3026x; 1.0070x over previous
//
#include <hip/hip_runtime.h>
#include <hip/hip_bf16.h>

#define B_ 16
#define N_ 358
#define P_ 72
#define D_ 96
#define ND_ 64
#define H_ 4
#define NH_ 4
#define HD_ 24
#define K_ 10
#define BN_ (B_*N_)     /* 5728 */
#define NN_ (N_*N_)     /* 128164 */
#define RPW_ 6          /* ceil(358/64) elements per lane in wave-per-row kernels */
#define NR5 5           /* rows per 32-lane group in attn (16 groups x 5 = 80 padded rows) */

__device__ __forceinline__ float gelu_f(float x){ return 0.5f*x*(1.0f+erff(x*0.7071067811865476f)); }
__device__ __forceinline__ float sigm_f(float x){ return 1.0f/(1.0f+expf(-x)); }

// ---------------------------------------------------------------------------
// Kernel 0: pack weights k-chunked so attn weight loads are WIDE and
// COALESCED (R4 scar: [c][k] transposed layout gave lane-stride 384B ->
// uncoalesced b128 -> +22% regression. Fix: chunk k, keep c adjacent):
//   wqkv_p[k2][c][2]: c=0..287 (q|k|v concat), = w[2*k2+kk][c%96]
//     -> P1 lane reads dwordx2 at lane-stride 8B (contiguous).
//   wo_p[d4][c][4]: = wo[4*d4+kk][c]
//     -> Oproj lane reads dwordx4 at lane-stride 16B (contiguous).
// ---------------------------------------------------------------------------
__global__ __launch_bounds__(256) void packw_kernel(
    const float* __restrict__ wq, const float* __restrict__ wk,
    const float* __restrict__ wv, const float* __restrict__ wo,
    float* __restrict__ wqkv_p, float* __restrict__ wo_p)
{
    const int gid = blockIdx.x*256 + threadIdx.x;
    if (gid < 48*288) {                 // wqkv_p: 48 k2-chunks x 288 cols x 2
        const int k2 = gid / 288, c = gid % 288;
        const float* src = (c < 96) ? wq : (c < 192) ? wk : wv;
        const int cc = (c >= 192) ? c-192 : (c >= 96) ? c-96 : c;
        wqkv_p[gid*2+0] = src[(2*k2+0)*D_ + cc];
        wqkv_p[gid*2+1] = src[(2*k2+1)*D_ + cc];
    }
    if (gid < 24*96) {                  // wo_p: 24 d4-chunks x 96 cols x 4
        const int d4 = gid / 96, c = gid % 96;
        wo_p[gid*4+0] = wo[(4*d4+0)*D_ + c];
        wo_p[gid*4+1] = wo[(4*d4+1)*D_ + c];
        wo_p[gid*4+2] = wo[(4*d4+2)*D_ + c];
        wo_p[gid*4+3] = wo[(4*d4+3)*D_ + c];
    }
}

// ---------------------------------------------------------------------------
// Kernel 1: temporal attention + node embedding (one block per (b,n) sequence)
//
// LAUNCH-BOUNDS SCAR (R1): 2nd arg = min blocks/CU on this toolchain.
// (512,4) -> cap 64 -> 33GB spill. (512,2) -> 16 waves/CU, cap 128. KEEP.
// SPILL SCAR (R2): chunk-4 temps without "#pragma unroll 1" overflowed the
// cap. All hot loops keep unroll 1.
// COALESCING SCAR (R4): [c][k] weight loads (lane-stride 384B) cost +22%.
// Packed layouts (packw_kernel) are wide AND coalesced (R6: 2182us, VALU 44.5).
//
// BARRIER RESTRUCTURE (R7): R6 counters showed stall-bound (VALUBusy 44.5%,
// wall ~2.2x issue time) with all 16 waves/CU barrier-locked into the same
// phase (3 barriers/head). att (softmax->PV) and obuf (PV->Oproj) are
// written/read ONLY by the owning half-wave group (rows rbase..rbase+4 are
// group-exclusive; a group is lanes 0-31 or 32-63 of ONE wave), and LDS ops
// from one wave execute in order on the DS pipe -> no block barrier needed.
// Only qh/kh/vhT cross waves. So: scores->softmax->PV->Oproj barrier-free,
// then ONE barrier (cross-wave reads done) -> stage(h+1) -> ONE barrier.
// 12 -> 8 barriers; waves drift and cover each other's LDS latency.
//
// LDS pool (floats): qh[80][28]=2240 @0 | kh[96][28]=2688 @2240 |
//  vhT[24][84]=2016 @4928 | att[80][76]=6080 @6944 | obuf[80][28]=2240 @13024
//  xs/ats [80][100]=8000 @0 (phase-ordered overlap). Total 15264 = 61.1KB.
//  kh rows 80..95 unwritten garbage, consumed only by masked lanes — safe.
// ---------------------------------------------------------------------------
__global__ __launch_bounds__(512, 2) void attn_kernel(
    const float* __restrict__ patch, const float* __restrict__ pos,
    const float* __restrict__ wqkv_p, const float* __restrict__ bq,
    const float* __restrict__ bk, const float* __restrict__ bv,
    const float* __restrict__ wo_p, const float* __restrict__ bo,
    const float* __restrict__ tng, const float* __restrict__ tnb,
    float* __restrict__ node_out, float* __restrict__ meanpr_out)
{
    __shared__ __align__(16) float pool[15264];
    __shared__ float rr[80];
    __shared__ float nb[D_];
    __shared__ float st2[2];

    float* const xs   = pool;           // [80][100] phase 1
    float* const qh   = pool;           // [80][28]
    float* const kh   = pool + 2240;    // [96][28]
    float* const vhT  = pool + 4928;    // [24][84]
    float* const att  = pool + 6944;    // [80][76]
    float* const obuf = pool + 13024;   // [80][28]
    float* const ats  = pool;           // [80][100] epilogue

    const int tid = threadIdx.x;
    const int tc  = tid & 31;
    const int tr  = tid >> 5;           // 0..15
    const int rbase = tr * NR5;         // 0,5,...,75
    const int bn  = blockIdx.x;
    const float* pr = patch + (size_t)bn * (P_*D_);

    // mean over P of pr (node_f) -- kept in a register by threads tid<96
    float mpr = 0.f;
    if (tid < D_) {
        #pragma unroll 1
        for (int p = 0; p < P_; ++p) mpr += pr[p*D_+tid];
        mpr *= (1.0f/P_);
        meanpr_out[(size_t)bn*D_ + tid] = mpr;
    }

    // load X = pr + pos into LDS [80][100]; rows 72..79 and cols 96..99 zero
    #pragma unroll 1
    for (int e = tid; e < 80*100; e += 512) {
        const int row = e / 100, col = e - row*100;
        xs[e] = (row < P_ && col < D_) ? (pr[row*D_+col] + pos[row*D_+col]) : 0.f;
    }
    __syncthreads();

    // ---- phase 1: Q,K,V = X @ W + b. SINGLE pass over k (xs read once),
    //      chunk-2, packed dwordx2 weight loads (coalesced). ~85 regs. ----
    float aq[3][NR5], ak[3][NR5], av[3][NR5];
    #pragma unroll
    for (int j = 0; j < 3; ++j) {
        const int c = tc + 32*j;
        const float vbq = bq[c], vbk = bk[c], vbv = bv[c];
        #pragma unroll
        for (int i = 0; i < NR5; ++i) { aq[j][i]=vbq; ak[j][i]=vbk; av[j][i]=vbv; }
    }
    {
        const float* wp = wqkv_p + (size_t)tc*2;    // + k2*576 per iter
        #pragma unroll 1
        for (int k2 = 0; k2 < 48; ++k2) {
            float2 xv[NR5];
            #pragma unroll
            for (int i = 0; i < NR5; ++i)
                xv[i] = *reinterpret_cast<const float2*>(&xs[(rbase+i)*100 + 2*k2]);
            float2 wq2[3], wk2[3], wv2[3];
            const float* wpk = wp + (size_t)k2*576;
            #pragma unroll
            for (int j = 0; j < 3; ++j) {
                wq2[j] = *reinterpret_cast<const float2*>(&wpk[(32*j)*2]);
                wk2[j] = *reinterpret_cast<const float2*>(&wpk[(96+32*j)*2]);
                wv2[j] = *reinterpret_cast<const float2*>(&wpk[(192+32*j)*2]);
            }
            #pragma unroll
            for (int j = 0; j < 3; ++j)
                #pragma unroll
                for (int i = 0; i < NR5; ++i) {
                    aq[j][i] = fmaf(xv[i].x, wq2[j].x, fmaf(xv[i].y, wq2[j].y, aq[j][i]));
                    ak[j][i] = fmaf(xv[i].x, wk2[j].x, fmaf(xv[i].y, wk2[j].y, ak[j][i]));
                    av[j][i] = fmaf(xv[i].x, wv2[j].x, fmaf(xv[i].y, wv2[j].y, av[j][i]));
                }
        }
    }
    __syncthreads();        // all xs reads done; pool free for head buffers

    const float rs = 0.20412414523193154f;      // 1/sqrt(24)

    // attended accumulators (output of o @ wo + bo), live across heads
    float ao[3][NR5];
    #pragma unroll
    for (int j = 0; j < 3; ++j) {
        const float vbo = bo[tc + 32*j];
        #pragma unroll
        for (int i = 0; i < NR5; ++i) ao[j][i] = vbo;
    }

    // stage head hh's Q (pre-scaled by rs), K, V^T slices from registers
    auto stage = [&](int hh) {
        #pragma unroll
        for (int j = 0; j < 3; ++j) {
            const int c = tc + 32*j;
            const int dl = c - HD_*hh;
            if ((unsigned)dl < (unsigned)HD_) {
                #pragma unroll
                for (int i = 0; i < NR5; ++i) {
                    const int row = rbase + i;
                    qh [row*28 + dl] = aq[j][i] * rs;
                    kh [row*28 + dl] = ak[j][i];
                    vhT[dl*84 + row] = av[j][i];
                }
            }
        }
    };

    stage(0);
    __syncthreads();    // A0: head-0 qh/kh/vhT visible

    #pragma unroll 1
    for (int h = 0; h < NH_; ++h) {
        // ---- scores S = (Q*rs) K^T (chunk-4, b128 both sides) ----
        float sc[3][NR5];
        #pragma unroll
        for (int j = 0; j < 3; ++j)
            #pragma unroll
            for (int i = 0; i < NR5; ++i) sc[j][i] = 0.f;
        #pragma unroll 1
        for (int d0 = 0; d0 < HD_; d0 += 4) {
            float4 qv[NR5];
            #pragma unroll
            for (int i = 0; i < NR5; ++i)
                qv[i] = *reinterpret_cast<const float4*>(&qh[(rbase+i)*28 + d0]);
            float4 kv[3];
            #pragma unroll
            for (int j = 0; j < 3; ++j) {
                const int jn = tc + 32*j;       // <=95 < 96 rows of kh
                kv[j] = *reinterpret_cast<const float4*>(&kh[jn*28 + d0]);
            }
            #pragma unroll
            for (int j = 0; j < 3; ++j)
                #pragma unroll
                for (int i = 0; i < NR5; ++i)
                    sc[j][i] = fmaf(qv[i].x, kv[j].x,
                               fmaf(qv[i].y, kv[j].y,
                               fmaf(qv[i].z, kv[j].z,
                               fmaf(qv[i].w, kv[j].w, sc[j][i]))));
        }

        // ---- in-register row softmax (row owned by one 32-lane group) ----
        // att rows rbase..rbase+4 are written and later read ONLY by this
        // group (same wave) -> no block barrier needed before PV.
        #pragma unroll
        for (int i = 0; i < NR5; ++i) {
            float m = fmaxf(sc[0][i], sc[1][i]);
            if (tc < 8) m = fmaxf(m, sc[2][i]);         // jn=64+tc valid iff tc<8
            #pragma unroll
            for (int s = 1; s < 32; s <<= 1) m = fmaxf(m, __shfl_xor(m, s, 32));
            const float e0 = __expf(sc[0][i]-m);
            const float e1 = __expf(sc[1][i]-m);
            const float e2 = (tc < 8) ? __expf(sc[2][i]-m) : 0.f;
            float sm = e0 + e1 + e2;
            #pragma unroll
            for (int s = 1; s < 32; s <<= 1) sm += __shfl_xor(sm, s, 32);
            const float inv = 1.0f/sm;
            const int row = rbase + i;
            att[row*76 + tc]      = e0*inv;
            att[row*76 + tc + 32] = e1*inv;
            if (tc < 8) att[row*76 + tc + 64] = e2*inv;
        }
        // (no __syncthreads: same-wave DS-pipe ordering suffices for att)

        // ---- PV: O[row][tc] = sum_j P[row][j] V[j][tc]  (tc < 24) ----
        // reads att (own rows, same wave) + vhT (cross-wave but stable
        // since barrier A of this head).
        if (tc < HD_) {
            float ov[NR5];
            #pragma unroll
            for (int i = 0; i < NR5; ++i) ov[i] = 0.f;
            #pragma unroll 1
            for (int j0 = 0; j0 < P_; j0 += 4) {
                const float4 vv = *reinterpret_cast<const float4*>(&vhT[tc*84 + j0]);
                #pragma unroll
                for (int i = 0; i < NR5; ++i) {
                    const float4 pa = *reinterpret_cast<const float4*>(&att[(rbase+i)*76 + j0]);
                    ov[i] = fmaf(pa.x, vv.x,
                            fmaf(pa.y, vv.y,
                            fmaf(pa.z, vv.z,
                            fmaf(pa.w, vv.w, ov[i]))));
                }
            }
            #pragma unroll
            for (int i = 0; i < NR5; ++i) obuf[(rbase+i)*28 + tc] = ov[i];
        }
        // (no __syncthreads: obuf rows are group-exclusive, same wave)

        // ---- Oproj: attended += O @ wo[24h..24h+23, :]; packed dwordx4 ----
        #pragma unroll 1
        for (int d4 = 6*h; d4 < 6*h+6; ++d4) {
            float4 ov4[NR5];
            #pragma unroll
            for (int i = 0; i < NR5; ++i)
                ov4[i] = *reinterpret_cast<const float4*>(&obuf[(rbase+i)*28 + (d4-6*h)*4]);
            float4 w4[3];
            #pragma unroll
            for (int j = 0; j < 3; ++j)
                w4[j] = *reinterpret_cast<const float4*>(&wo_p[(d4*96 + tc+32*j)*4]);
            #pragma unroll
            for (int j = 0; j < 3; ++j)
                #pragma unroll
                for (int i = 0; i < NR5; ++i)
                    ao[j][i] = fmaf(ov4[i].x, w4[j].x,
                               fmaf(ov4[i].y, w4[j].y,
                               fmaf(ov4[i].z, w4[j].z,
                               fmaf(ov4[i].w, w4[j].w, ao[j][i]))));
        }

        __syncthreads();    // C': ALL waves done reading qh/kh/vhT this head
        if (h < NH_-1) {
            stage(h+1);     // overwrite qh/kh/vhT (safe after C')
            __syncthreads();    // A: staged data visible before next scores
        }
    }

    // ---- epilogue: attended -> LDS, imp softmax, node, LN ----
    // (last barrier was C' of h=3: ats overwrite of qh/kh/att pool is safe)
    #pragma unroll
    for (int j = 0; j < 3; ++j) {
        const int c = tc + 32*j;
        #pragma unroll
        for (int i = 0; i < NR5; ++i) ats[(rbase+i)*100 + c] = ao[j][i];
    }
    __syncthreads();

    if (tid < P_) {                         // row mean over D
        const float* ar = ats + tid*100;
        float s = 0.f;
        #pragma unroll 1
        for (int d = 0; d < D_; ++d) s += ar[d];
        rr[tid] = s*(1.0f/D_);
    }
    __syncthreads();
    if (tid < 64) {                         // imp = softmax over P (wave 0)
        const float a0 = rr[tid];
        const float a1 = (tid < 8) ? rr[64+tid] : -3.0e38f;
        float mx = fmaxf(a0, a1);
        #pragma unroll
        for (int s = 1; s < 64; s <<= 1) mx = fmaxf(mx, __shfl_xor(mx, s));
        const float e0 = __expf(a0-mx);
        const float e1 = (tid < 8) ? __expf(a1-mx) : 0.f;
        float sm = e0 + e1;
        #pragma unroll
        for (int s = 1; s < 64; s <<= 1) sm += __shfl_xor(sm, s);
        const float inv = 1.0f/sm;
        rr[tid] = e0*inv;
        if (tid < 8) rr[64+tid] = e1*inv;
    }
    __syncthreads();
    if (tid < D_) {
        float s = 0.f;
        #pragma unroll 1
        for (int i = 0; i < P_; ++i) s += ats[i*100+tid]*rr[i];
        nb[tid] = s + mpr;
    }
    __syncthreads();
    if (tid < 64) {                         // LN stats (wave 0)
        const float x0 = nb[tid];
        const float x1 = (tid < 32) ? nb[64+tid] : 0.f;
        float sm = x0 + x1;
        float sq = x0*x0 + x1*x1;
        #pragma unroll
        for (int s = 1; s < 64; s <<= 1) { sm += __shfl_xor(sm, s); sq += __shfl_xor(sq, s); }
        if (tid == 0) {
            const float m = sm*(1.0f/D_);
            const float v = sq*(1.0f/D_) - m*m;
            st2[0] = m; st2[1] = rsqrtf(v + 1e-5f);
        }
    }
    __syncthreads();
    if (tid < D_) {
        const float y = (nb[tid]-st2[0])*st2[1]*tng[tid] + tnb[tid];
        node_out[(size_t)bn*D_+tid] = y;
    }
}

// ---------------------------------------------------------------------------
// Kernel 2: h1 = gelu(LN(node @ de_w1 + b1))
// ---------------------------------------------------------------------------
__global__ __launch_bounds__(128) void enc1_kernel(
    const float* __restrict__ node, const float* __restrict__ w1, const float* __restrict__ b1,
    const float* __restrict__ g1, const float* __restrict__ be1, float* __restrict__ h1)
{
    __shared__ float nr[D_];
    __shared__ float buf[128];
    __shared__ float st2[2];
    const int tid = threadIdx.x; const int bn = blockIdx.x;
    if (tid < D_) nr[tid] = node[(size_t)bn*D_+tid];
    __syncthreads();
    float s = b1[tid];
    for (int c = 0; c < D_; ++c) s += nr[c]*w1[c*128+tid];
    buf[tid] = s;
    __syncthreads();
    if (tid == 0) {
        float m=0.f; for(int d=0;d<128;++d) m+=buf[d]; m *= (1.0f/128.0f);
        float v=0.f; for(int d=0;d<128;++d){ float df=buf[d]-m; v+=df*df; } v *= (1.0f/128.0f);
        st2[0]=m; st2[1]=rsqrtf(v+1e-5f);
    }
    __syncthreads();
    float y = (buf[tid]-st2[0])*st2[1]*g1[tid] + be1[tid];
    h1[(size_t)bn*128+tid] = gelu_f(y);
}

// ---------------------------------------------------------------------------
// Kernel 3: dyn = LN(h1 @ de_w2 + b2)
// ---------------------------------------------------------------------------
__global__ __launch_bounds__(64) void enc2_kernel(
    const float* __restrict__ h1, const float* __restrict__ w2, const float* __restrict__ b2,
    const float* __restrict__ g2, const float* __restrict__ be2, float* __restrict__ dyn)
{
    __shared__ float hr[128];
    __shared__ float buf[ND_];
    __shared__ float st2[2];
    const int tid = threadIdx.x; const int bn = blockIdx.x;
    hr[tid] = h1[(size_t)bn*128+tid];
    hr[tid+64] = h1[(size_t)bn*128+64+tid];
    __syncthreads();
    float s = b2[tid];
    for (int c = 0; c < 128; ++c) s += hr[c]*w2[c*ND_+tid];
    buf[tid] = s;
    __syncthreads();
    if (tid == 0) {
        float m=0.f; for(int d=0;d<ND_;++d) m+=buf[d]; m *= (1.0f/ND_);
        float v=0.f; for(int d=0;d<ND_;++d){ float df=buf[d]-m; v+=df*df; } v *= (1.0f/ND_);
        st2[0]=m; st2[1]=rsqrtf(v+1e-5f);
    }
    __syncthreads();
    dyn[(size_t)bn*ND_+tid] = (buf[tid]-st2[0])*st2[1]*g2[tid] + be2[tid];
}

// ---------------------------------------------------------------------------
// Kernel 4: one GNN layer (one block per (b,n) row)
// ---------------------------------------------------------------------------
__global__ __launch_bounds__(256) void gnn_kernel(
    const float* __restrict__ din, float* __restrict__ dout,
    const float* __restrict__ gw, const float* __restrict__ gb,
    const float* __restrict__ gg, const float* __restrict__ gbe, int layer)
{
    __shared__ float dq[ND_];
    __shared__ float prob[N_];
    __shared__ float red[256];
    __shared__ float aggp[4*ND_];
    __shared__ float buf[ND_];
    __shared__ float st2[2];
    const int tid = threadIdx.x; const int bn = blockIdx.x;
    const int b = bn / N_;
    const float* base = din + (size_t)b*N_*ND_;
    if (tid < ND_) dq[tid] = din[(size_t)bn*ND_+tid];
    __syncthreads();

    float lmax = -1e30f;
    for (int m = tid; m < N_; m += 256) {
        const float* rm = base + (size_t)m*ND_;
        float s = 0.f;
        for (int c = 0; c < ND_; ++c) s += dq[c]*rm[c];
        s *= 5.0f;                              // /0.2
        prob[m] = s;
        lmax = fmaxf(lmax, s);
    }
    red[tid]=lmax; __syncthreads();
    for (int st=128; st>0; st>>=1){ if(tid<st) red[tid]=fmaxf(red[tid],red[tid+st]); __syncthreads(); }
    const float mx = red[0]; __syncthreads();
    float lsum = 0.f;
    for (int m=tid; m<N_; m+=256){ float ev=expf(prob[m]-mx); prob[m]=ev; lsum+=ev; }
    red[tid]=lsum; __syncthreads();
    for (int st=128; st>0; st>>=1){ if(tid<st) red[tid]+=red[tid+st]; __syncthreads(); }
    const float inv = 1.0f/red[0]; __syncthreads();
    for (int m=tid; m<N_; m+=256) prob[m]*=inv;
    __syncthreads();

    {   // agg = sim @ dyn
        const int part = tid >> 6, d = tid & 63;
        float s = 0.f;
        for (int m = part; m < N_; m += 4) s += prob[m]*base[(size_t)m*ND_+d];
        aggp[part*ND_+d] = s;
    }
    __syncthreads();
    if (tid < ND_)
        aggp[tid] = aggp[tid]+aggp[ND_+tid]+aggp[2*ND_+tid]+aggp[3*ND_+tid];
    __syncthreads();
    if (tid < ND_) {
        float t = gb[layer*ND_+tid];
        for (int c = 0; c < ND_; ++c) t += aggp[c]*gw[(layer*ND_+c)*ND_+tid];
        buf[tid] = t;
    }
    __syncthreads();
    if (tid == 0) {
        float m=0.f; for(int d=0;d<ND_;++d) m+=buf[d]; m *= (1.0f/ND_);
        float v=0.f; for(int d=0;d<ND_;++d){ float df=buf[d]-m; v+=df*df; } v *= (1.0f/ND_);
        st2[0]=m; st2[1]=rsqrtf(v+1e-5f);
    }
    __syncthreads();
    if (tid < ND_) {
        float y = (buf[tid]-st2[0])*st2[1]*gg[layer*ND_+tid] + gbe[layer*ND_+tid];
        dout[(size_t)bn*ND_+tid] = gelu_f(y) + dq[tid];
    }
}

// ---------------------------------------------------------------------------
// Wave-per-row softmax + top-k + renormalize + store. No __syncthreads.
// lv[j] = relu'd, temperature-scaled logits at positions m = lane + 64*j.
// Tie-break: max value, lowest index (matches lax.top_k stability).
// ---------------------------------------------------------------------------
__device__ __forceinline__ void wave_softmax_topk_store(
    float lv[RPW_], int lane, float* __restrict__ outrow)
{
    float mx = 0.f;                     // logits >= 0 (post-relu), 0 is a valid floor
    #pragma unroll
    for (int j=0;j<RPW_;++j) mx = fmaxf(mx, lv[j]);
    #pragma unroll
    for (int s=1;s<64;s<<=1) mx = fmaxf(mx, __shfl_xor(mx, s));
    float sm = 0.f;
    #pragma unroll
    for (int j=0;j<RPW_;++j) {
        const int m = lane + 64*j;
        const float e = (m < N_) ? expf(lv[j]-mx) : 0.f;
        lv[j] = e; sm += e;
    }
    #pragma unroll
    for (int s=1;s<64;s<<=1) sm += __shfl_xor(sm, s);
    const float inv = 1.0f/sm;
    #pragma unroll
    for (int j=0;j<RPW_;++j) lv[j] *= inv;

    unsigned sel = 0u;
    float ksum = 0.f;
    for (int it = 0; it < K_; ++it) {
        float bv = -1.f; int bm = 0x7fffffff;
        #pragma unroll
        for (int j=0;j<RPW_;++j) {
            const int m = lane + 64*j;
            if (m < N_ && !((sel>>j)&1u) && lv[j] > bv) { bv = lv[j]; bm = m; }
        }
        #pragma unroll
        for (int s=1;s<64;s<<=1) {
            const float ov = __shfl_xor(bv, s);
            const int   om = __shfl_xor(bm, s);
            if (ov > bv || (ov == bv && om < bm)) { bv = ov; bm = om; }
        }
        ksum += bv;
        if ((bm & 63) == lane) sel |= 1u << (bm >> 6);
    }
    const float dn = 1.0f/(ksum + 1e-8f);
    #pragma unroll
    for (int j=0;j<RPW_;++j) {
        const int m = lane + 64*j;
        if (m < N_) outrow[m] = ((sel>>j)&1u) ? lv[j]*dn : 0.f;
    }
}

// ---------------------------------------------------------------------------
// Kernel 5: static adjacency — one WAVE per (h,n) row; 4 rows per block
// ---------------------------------------------------------------------------
__global__ __launch_bounds__(256) void static_adj_kernel(
    const float* __restrict__ le1, const float* __restrict__ le2,
    const float* __restrict__ ge1, const float* __restrict__ ge2,
    const float* __restrict__ temp, float* __restrict__ outs)
{
    __shared__ float e1l[4][ND_];
    const int tid = threadIdx.x;
    const int wv = tid >> 6, lane = tid & 63;
    const int r = blockIdx.x*4 + wv;        // r = h*N_ + n, grid = H_*N_/4
    const int h = r / N_, n = r % N_;
    if (h < 2) { if (lane < 32) e1l[wv][lane] = le1[(h*N_+n)*32+lane]; }
    else       { e1l[wv][lane] = ge1[((h-2)*N_+n)*64+lane]; }
    __syncthreads();
    const float t = temp[h];
    const float tl = (h < 2) ? fminf(fmaxf(t*2.0f,0.1f),5.0f) : fminf(fmaxf(t*0.5f,0.1f),2.0f);
    const float invt = 1.0f/tl;
    float lv[RPW_];
    #pragma unroll
    for (int j=0;j<RPW_;++j) lv[j] = 0.f;
    if (h < 2) {
        for (int c = 0; c < 32; ++c) {
            const float dc = e1l[wv][c];
            const float* sr = le2 + (size_t)(h*32+c)*N_;
            #pragma unroll
            for (int j=0;j<RPW_;++j) {
                const int m = lane + 64*j;
                if (m < N_) lv[j] += dc*sr[m];
            }
        }
    } else {
        for (int c = 0; c < 64; ++c) {
            const float dc = e1l[wv][c];
            const float* sr = ge2 + (size_t)((h-2)*64+c)*N_;
            #pragma unroll
            for (int j=0;j<RPW_;++j) {
                const int m = lane + 64*j;
                if (m < N_) lv[j] += dc*sr[m];
            }
        }
    }
    #pragma unroll
    for (int j=0;j<RPW_;++j) lv[j] = fmaxf(lv[j],0.f)*invt;
    wave_softmax_topk_store(lv, lane, outs + (size_t)r*N_);
}

// ---------------------------------------------------------------------------
// Kernel 6: dynamic adjacency — one WAVE per (b,h,n) row; 4 rows per block
// ---------------------------------------------------------------------------
__global__ __launch_bounds__(256) void dyn_adj_kernel(
    const float* __restrict__ dyn, const float* __restrict__ se2,
    const float* __restrict__ temp, float* __restrict__ outd)
{
    __shared__ float dql[4][ND_];
    const int tid = threadIdx.x;
    const int wv = tid >> 6, lane = tid & 63;
    const int r = blockIdx.x*4 + wv;        // grid = B_*H_*N_/4 = 5728
    const int b = r / (H_*N_);
    const int rem = r % (H_*N_);
    const int h = rem / N_, n = rem % N_;
    dql[wv][lane] = dyn[((size_t)(b*N_+n))*ND_ + lane];
    __syncthreads();
    const float invt = 1.0f/fminf(fmaxf(temp[h],0.1f),2.0f);
    float lv[RPW_];
    #pragma unroll
    for (int j=0;j<RPW_;++j) lv[j] = 0.f;
    const float* sb = se2 + (size_t)h*ND_*N_;
    for (int c = 0; c < ND_; ++c) {
        const float dc = dql[wv][c];
        const float* sr = sb + (size_t)c*N_;
        #pragma unroll
        for (int j=0;j<RPW_;++j) {
            const int m = lane + 64*j;
            if (m < N_) lv[j] += dc*sr[m];
        }
    }
    #pragma unroll
    for (int j=0;j<RPW_;++j) lv[j] = fmaxf(lv[j],0.f)*invt;
    wave_softmax_topk_store(lv, lane, outd + ((size_t)(b*H_+h)*N_+n)*(size_t)N_);
}

// ---------------------------------------------------------------------------
// Kernel 7: fusion gate  w = sigmoid(node_f @ gf_w + gf_b)
// ---------------------------------------------------------------------------
__global__ __launch_bounds__(256) void fw_kernel(
    const float* __restrict__ meanpr, const float* __restrict__ gfw,
    const float* __restrict__ gfb, float* __restrict__ wf)
{
    const int gid = blockIdx.x*256 + threadIdx.x;
    if (gid >= BN_*H_) return;
    const int bn = gid >> 2, h = gid & 3;
    float s = gfb[h];
    const float* mp = meanpr + (size_t)bn*D_;
    for (int c=0;c<D_;++c) s += mp[c]*gfw[c*H_+h];
    wf[gid] = sigm_f(s);
}

// ---------------------------------------------------------------------------
// Kernel 8: fusion + edge-encoder MLP + final (one thread per (b,n,m))
// ---------------------------------------------------------------------------
__global__ __launch_bounds__(256) void edge_kernel(
    const float* __restrict__ staticf, const float* __restrict__ dynf,
    const float* __restrict__ wf,
    const float* __restrict__ ew1, const float* __restrict__ eb1,
    const float* __restrict__ eg,  const float* __restrict__ ebe,
    const float* __restrict__ ew2, const float* __restrict__ eb2,
    const float* __restrict__ ew3, const float* __restrict__ eb3,
    float* __restrict__ outf)
{
    __shared__ float w1s[64], w2s[128], b1s[16], gs[16], bes[16], b2s[8], w3s[8];
    __shared__ float b3v;
    const int tid = threadIdx.x;
    if (tid < 64)                 w1s[tid]     = ew1[tid];
    else if (tid < 192)           w2s[tid-64]  = ew2[tid-64];
    else if (tid < 208)           b1s[tid-192] = eb1[tid-192];
    else if (tid < 224)           gs[tid-208]  = eg[tid-208];
    else if (tid < 240)           bes[tid-224] = ebe[tid-224];
    else if (tid < 248)           b2s[tid-240] = eb2[tid-240];
    else                          w3s[tid-248] = ew3[tid-248];
    if (tid == 0) b3v = eb3[0];
    __syncthreads();

    const size_t gid = (size_t)blockIdx.x*256 + tid;
    if (gid >= (size_t)B_*NN_) return;
    const int m = (int)(gid % N_);
    const size_t t1 = gid / N_;
    const int n = (int)(t1 % N_);
    const int b = (int)(t1 / N_);

    const float* wrow = wf + ((size_t)(b*N_+n))*4;
    float mh[4]; float msum = 0.f;
    #pragma unroll
    for (int h=0; h<4; ++h) {
        float w  = wrow[h];
        float st = staticf[((size_t)(h*N_+n))*N_ + m];
        float da = dynf[(((size_t)(b*4+h))*N_+n)*(size_t)N_ + m];
        float f = (1.0f-w)*st + w*da;
        mh[h] = f; msum += f;
    }
    float e16[16]; float mean = 0.f;
    #pragma unroll
    for (int j=0;j<16;++j) {
        float s = b1s[j];
        #pragma unroll
        for (int h=0;h<4;++h) s += mh[h]*w1s[h*16+j];
        e16[j] = s; mean += s;
    }
    mean *= (1.0f/16.0f);
    float var = 0.f;
    #pragma unroll
    for (int j=0;j<16;++j){ float df=e16[j]-mean; var += df*df; }
    var *= (1.0f/16.0f);
    const float rinv = rsqrtf(var + 1e-5f);
    #pragma unroll
    for (int j=0;j<16;++j) e16[j] = gelu_f((e16[j]-mean)*rinv*gs[j] + bes[j]);
    float e8[8];
    #pragma unroll
    for (int o=0;o<8;++o) {
        float s = b2s[o];
        #pragma unroll
        for (int j=0;j<16;++j) s += e16[j]*w2s[j*8+o];
        e8[o] = gelu_f(s);
    }
    float e = b3v;
    #pragma unroll
    for (int o=0;o<8;++o) e += e8[o]*w3s[o];
    outf[gid] = sigm_f(e) * (msum*0.25f);
}

// ---------------------------------------------------------------------------
extern "C" void kernel_launch(void* const* d_in, const int* in_sizes, int n_in,
                              void* d_out, int out_size, void* d_ws, size_t ws_size,
                              hipStream_t stream)
{
    const float* patch = (const float*)d_in[0];
    const float* le1   = (const float*)d_in[1];
    const float* le2   = (const float*)d_in[2];
    const float* ge1   = (const float*)d_in[3];
    const float* ge2   = (const float*)d_in[4];
    const float* se2   = (const float*)d_in[5];
    const float* temp  = (const float*)d_in[6];
    const float* pos   = (const float*)d_in[7];
    const float* wq    = (const float*)d_in[8];
    const float* bq    = (const float*)d_in[9];
    const float* wk    = (const float*)d_in[10];
    const float* bk    = (const float*)d_in[11];
    const float* wv    = (const float*)d_in[12];
    const float* bv    = (const float*)d_in[13];
    const float* wo    = (const float*)d_in[14];
    const float* bo    = (const float*)d_in[15];
    const float* tng   = (const float*)d_in[16];
    const float* tnb   = (const float*)d_in[17];
    const float* dw1   = (const float*)d_in[18];
    const float* db1   = (const float*)d_in[19];
    const float* dg1   = (const float*)d_in[20];
    const float* dbe1  = (const float*)d_in[21];
    const float* dw2   = (const float*)d_in[22];
    const float* db2   = (const float*)d_in[23];
    const float* dg2   = (const float*)d_in[24];
    const float* dbe2  = (const float*)d_in[25];
    const float* gw    = (const float*)d_in[26];
    const float* gb    = (const float*)d_in[27];
    const float* gg    = (const float*)d_in[28];
    const float* gbe   = (const float*)d_in[29];
    const float* gfw   = (const float*)d_in[30];
    const float* gfb   = (const float*)d_in[31];
    const float* ew1   = (const float*)d_in[32];
    const float* eb1   = (const float*)d_in[33];
    const float* eg    = (const float*)d_in[34];
    const float* ebe   = (const float*)d_in[35];
    const float* ew2   = (const float*)d_in[36];
    const float* eb2   = (const float*)d_in[37];
    const float* ew3   = (const float*)d_in[38];
    const float* eb3   = (const float*)d_in[39];
    (void)in_sizes; (void)n_in; (void)out_size; (void)ws_size;

    // workspace layout: BN*384 floats (8.8 MB) + packed weights
    float* ws      = (float*)d_ws;
    float* meanpr  = ws;                        // BN*96, live until fw_kernel
    float* node    = meanpr + (size_t)BN_*D_;   // BN*96; dead after enc1 -> reused as dyn1
    float* h1      = node   + (size_t)BN_*D_;   // BN*128; dead after enc2 -> reused as wfuse
    float* dyn0    = h1     + (size_t)BN_*128;  // BN*64
    float* dyn1    = node;                      // alias (gnn layer0 output)
    float* wfuse   = h1;                        // alias (BN*4)
    float* wqkv_p  = dyn0   + (size_t)BN_*ND_;  // 48*288*2 = 27648
    float* wo_p    = wqkv_p + 48*288*2;         // 24*96*4  = 9216

    float* out        = (float*)d_out;
    float* out_final  = out;
    float* out_static = out + (size_t)B_*NN_;
    float* out_dyn    = out_static + (size_t)H_*NN_;

    packw_kernel<<<(48*288+255)/256, 256, 0, stream>>>(wq,wk,wv,wo,wqkv_p,wo_p);
    attn_kernel<<<BN_, 512, 0, stream>>>(patch,pos,wqkv_p,bq,bk,bv,wo_p,bo,tng,tnb,node,meanpr);
    enc1_kernel<<<BN_, 128, 0, stream>>>(node,dw1,db1,dg1,dbe1,h1);
    enc2_kernel<<<BN_, 64,  0, stream>>>(h1,dw2,db2,dg2,dbe2,dyn0);
    gnn_kernel<<<BN_, 256, 0, stream>>>(dyn0,dyn1,gw,gb,gg,gbe,0);
    gnn_kernel<<<BN_, 256, 0, stream>>>(dyn1,dyn0,gw,gb,gg,gbe,1);
    static_adj_kernel<<<H_*N_/4, 256, 0, stream>>>(le1,le2,ge1,ge2,temp,out_static);
    dyn_adj_kernel<<<B_*H_*N_/4, 256, 0, stream>>>(dyn0,se2,temp,out_dyn);
    fw_kernel<<<(BN_*H_+255)/256, 256, 0, stream>>>(meanpr,gfw,gfb,wfuse);
    edge_kernel<<<((size_t)B_*NN_+255)/256, 256, 0, stream>>>(
        out_static,out_dyn,wfuse,ew1,eb1,eg,ebe,ew2,eb2,ew3,eb3,out_final);
}